// Round 9
// baseline (3729.715 us; speedup 1.0000x reference)
//
#include <hip/hip_runtime.h>
#include <cstdint>
#include <cstddef>

#define N_NODES 16384
#define N_EDGES 65536
#define NFEAT 128   // GRU hidden
#define NIN   64    // node inputs
#define NEDGE 128   // edge features
#define NOUTD 64    // node outputs
#define NITERS 7
#define NBLKS 512   // persistent grid: exactly 2 blocks/CU x 256 CUs

#define CHS 2080    // act chunk stride bytes (128 edges * 16B + 32B pad)

typedef _Float16 half8 __attribute__((ext_vector_type(8)));
typedef _Float16 half4 __attribute__((ext_vector_type(4)));
typedef float floatx4 __attribute__((ext_vector_type(4)));

#define MFMA16(a,b,c) __builtin_amdgcn_mfma_f32_16x16x32_f16((a),(b),(c),0,0,0)

// raw barrier (no vmcnt(0) drain, unlike __syncthreads)
#define SBAR() asm volatile("s_barrier" ::: "memory")
#define WAITLGKM() asm volatile("s_waitcnt lgkmcnt(0)" ::: "memory")
#define WAITV0() asm volatile("s_waitcnt vmcnt(0)" ::: "memory")

// async global->LDS, 16B per lane. Global src per-lane; LDS dest wave-uniform base (+lane*16 by HW).
__device__ __forceinline__ void load_lds16(const void* g, void* l){
  __builtin_amdgcn_global_load_lds(
      (__attribute__((address_space(1))) void*)(uintptr_t)g,
      (__attribute__((address_space(3))) void*)l,
      16, 0, 0);
}

// ---------------- device-wide barrier (2-level, generation-based) ----------------
// bar[grp*16] grp<8: group arrival counters (64 blocks each, separate cachelines)
// bar[128]: root counter; bar[144]: generation
// Correct only because all NBLKS blocks are co-resident (grid==capacity).
__device__ __forceinline__ void gridbar(int* bar){
  __threadfence();                 // release: push messages/h stores device-wide (cross-XCD)
  __syncthreads();
  if (threadIdx.x == 0){
    int g = __hip_atomic_load(&bar[144], __ATOMIC_RELAXED, __HIP_MEMORY_SCOPE_AGENT);
    int grp = blockIdx.x & 7;
    int a = __hip_atomic_fetch_add(&bar[grp*16], 1, __ATOMIC_ACQ_REL, __HIP_MEMORY_SCOPE_AGENT);
    if (a == (NBLKS/8 - 1)){
      __hip_atomic_store(&bar[grp*16], 0, __ATOMIC_RELAXED, __HIP_MEMORY_SCOPE_AGENT);
      int r = __hip_atomic_fetch_add(&bar[128], 1, __ATOMIC_ACQ_REL, __HIP_MEMORY_SCOPE_AGENT);
      if (r == 7){
        __hip_atomic_store(&bar[128], 0, __ATOMIC_RELAXED, __HIP_MEMORY_SCOPE_AGENT);
        __hip_atomic_store(&bar[144], g+1, __ATOMIC_RELEASE, __HIP_MEMORY_SCOPE_AGENT);
      } else {
        while (__hip_atomic_load(&bar[144], __ATOMIC_ACQUIRE, __HIP_MEMORY_SCOPE_AGENT) == g)
          __builtin_amdgcn_s_sleep(2);
      }
    } else {
      while (__hip_atomic_load(&bar[144], __ATOMIC_ACQUIRE, __HIP_MEMORY_SCOPE_AGENT) == g)
        __builtin_amdgcn_s_sleep(2);
    }
  }
  __syncthreads();
  __threadfence();                 // acquire side: invalidate stale L1/L2 lines
}

// ---------------- one-shot setup: inits + fp16 weight repack + bias concat ----------------
__global__ void setup_kernel(
    const float* __restrict__ node_inputs,
    const float* __restrict__ W1, const float* __restrict__ W2,
    const float* __restrict__ W3, const float* __restrict__ W4,
    const float* __restrict__ W_ih, const float* __restrict__ W_hh,
    const float* __restrict__ W_f,
    const float* __restrict__ b1, const float* __restrict__ b2,
    const float* __restrict__ b3, const float* __restrict__ b4,
    float* __restrict__ h32, _Float16* __restrict__ h16,
    _Float16* __restrict__ nin16,
    _Float16* __restrict__ W1s, _Float16* __restrict__ W2s, _Float16* __restrict__ W3s,
    _Float16* __restrict__ W4s, _Float16* __restrict__ Wihs, _Float16* __restrict__ Whhs,
    _Float16* __restrict__ Wfs, float* __restrict__ msgbias, int* __restrict__ cnt){
  int b = blockIdx.x, t = threadIdx.x;
  if (b < 8192){ int i=b*256+t; h32[i]=0.f; h16[i]=(_Float16)0.f; return; }
  b -= 8192;
  if (b < 4096){ int i=b*256+t; nin16[i] = (_Float16)node_inputs[i]; return; }
  b -= 4096;
  if (b < 64){ cnt[b*256+t] = 0; return; }
  b -= 64;
  if (b >= 176){  // bias concat: b1|b2|b3|b4 -> msgbias[1024] (zero-padded)
    int i = (b-176)*256 + t;
    float v = 0.f;
    if      (i < 256) v = b1[i];
    else if (i < 512) v = b2[i-256];
    else if (i < 768) v = b3[i-512];
    else if (i < 896) v = b4[i-768];
    msgbias[i] = v; return;
  }
  const float* W; _Float16* o; int NO, KI, base;
  if      (b < 32){ W=W1;  o=W1s;  NO=256; KI=256; base=b; }
  else if (b < 64){ W=W2;  o=W2s;  NO=256; KI=256; base=b-32; }
  else if (b < 96){ W=W3;  o=W3s;  NO=256; KI=256; base=b-64; }
  else if (b <112){ W=W4;  o=W4s;  NO=128; KI=256; base=b-96; }
  else if (b <148){ W=W_ih;o=Wihs; NO=384; KI=192; base=b-112; }
  else if (b <172){ W=W_hh;o=Whhs; NO=384; KI=128; base=b-148; }
  else            { W=W_f; o=Wfs;  NO=64;  KI=128; base=b-172; }
  int g = base*256 + t;
  int total = NO*(KI>>3);
  if (g >= total) return;
  int c = g/NO, j = g - c*NO;
  #pragma unroll
  for (int i=0;i<8;++i) o[(size_t)g*8+i] = (_Float16)W[(size_t)j*KI + c*8 + i];
}

__global__ void hist_kernel(const int* __restrict__ dst, int* __restrict__ cnt){
  int e = blockIdx.x*256+threadIdx.x; if (e<N_EDGES) atomicAdd(&cnt[dst[e]],1);
}
__global__ __launch_bounds__(1024) void scan_kernel(const int* __restrict__ cnt,
                                                    int* __restrict__ rowptr,
                                                    int* __restrict__ offs,
                                                    int* __restrict__ bar){
  __shared__ int sd[1024];
  int t = threadIdx.x;
  if (t < 256) bar[t] = 0;          // init device-barrier state each call
  int c[16]; int s=0;
  #pragma unroll
  for (int k=0;k<16;++k){ c[k]=cnt[t*16+k]; s+=c[k]; }
  sd[t]=s; __syncthreads();
  for (int off=1; off<1024; off<<=1){
    int v = (t>=off)? sd[t-off]:0;
    __syncthreads();
    sd[t]+=v;
    __syncthreads();
  }
  int base = sd[t]-s; // exclusive prefix
  #pragma unroll
  for (int k=0;k<16;++k){ rowptr[t*16+k]=base; offs[t*16+k]=base; base+=c[k]; }
  if (t==0) rowptr[N_NODES]=N_EDGES;
}
// CSR permutation: src/dst ids in CSR-slot order -> msg writes message rows
// contiguously in dst-grouped order (agg reads sequentially).
__global__ void scatter_kernel(const int* __restrict__ src, const int* __restrict__ dst,
                               int* __restrict__ offs,
                               int* __restrict__ src_csr, int* __restrict__ dst_csr){
  int e = blockIdx.x*256+threadIdx.x;
  if (e<N_EDGES){
    int d = dst[e];
    int p = atomicAdd(&offs[d],1);
    src_csr[p] = src[e];
    dst_csr[p] = d;
  }
}

// ---------------- msg phase: fused 4-layer edge MLP, 128 edges/block, 4 waves ----------------
// act LDS: [32 chunks][128 edges][8 halfs], chunk stride CHS. A frags from LDS (2M x 2N waves).
// B frags: global(L2) -> VGPR, double-buffered one full K-step ahead. No in-loop barriers.
template<int N, int NEXTN>
__device__ __forceinline__ void run_layer(const _Float16* __restrict__ Ws,
                                          const _Float16* __restrict__ nextWs,
                                          const char* act, half8 (&b)[2][8],
                                          int wave, int lane, floatx4 (&acc)[4][8]){
  constexpr int NTW  = N/32;
  constexpr int NNTW = (NEXTN>0)? NEXTN/32 : 0;
  const int kg = lane>>4, col = lane&15;
  const int wr = wave>>1, wc = wave&1;          // 2M x 2N wave grid
  const int j0  = wc*(N/2);
  const int j0n = wc*(NEXTN/2);
  const int r0  = wr*64;
  #pragma unroll
  for (int kk=0; kk<8; ++kk){
    if (kk < 7){
      #pragma unroll
      for (int nt=0; nt<NTW; ++nt)
        b[(kk+1)&1][nt] = *(const half8*)&Ws[(size_t)(((kk+1)*4+kg)*N + j0 + nt*16 + col)*8];
    } else if constexpr (NEXTN > 0){
      #pragma unroll
      for (int nt=0; nt<NNTW; ++nt)
        b[0][nt] = *(const half8*)&nextWs[(size_t)(kg*NEXTN + j0n + nt*16 + col)*8];
    }
    half8 a[4];
    #pragma unroll
    for (int mt=0; mt<4; ++mt)
      a[mt] = *(const half8*)(act + (size_t)(kk*4+kg)*CHS + (r0 + mt*16 + col)*16);
    __builtin_amdgcn_s_setprio(1);
    #pragma unroll
    for (int nt=0; nt<NTW; ++nt)
      #pragma unroll
      for (int mt=0; mt<4; ++mt)
        acc[mt][nt] = MFMA16(a[mt], b[kk&1][nt], acc[mt][nt]);
    __builtin_amdgcn_s_setprio(0);
  }
}

template<int NTW>
__device__ __forceinline__ void epi_relu(floatx4 (&acc)[4][8], const float* __restrict__ biasf,
                                         int boff, char* act, int wave, int lane){
  const int rg = lane>>4, col = lane&15;
  const int wr = wave>>1, wc = wave&1;
  const int r0 = wr*64;
  #pragma unroll
  for (int nt=0; nt<NTW; ++nt){
    int j = wc*(NTW*16) + nt*16 + col;
    float bv = biasf[boff + j];        // LDS read (lgkm) -- keeps vmcnt clean
    char* dst = act + (size_t)(j>>3)*CHS + (j&7)*2;
    #pragma unroll
    for (int mt=0; mt<4; ++mt){
      #pragma unroll
      for (int r=0; r<4; ++r){
        int e = r0 + mt*16 + rg*4 + r;
        float v = fmaxf(acc[mt][nt][r] + bv, 0.f);
        acc[mt][nt][r] = 0.f;
        *(_Float16*)(dst + (size_t)e*16) = (_Float16)v;
      }
    }
  }
}

__device__ __forceinline__ void msg_phase(
    const _Float16* __restrict__ h,
    const int* __restrict__ src_csr, const int* __restrict__ dst_csr,
    const _Float16* __restrict__ W1s, const _Float16* __restrict__ W2s,
    const _Float16* __restrict__ W3s, const _Float16* __restrict__ W4s,
    _Float16* __restrict__ messages,
    char* smem, int wave, int lane){
  char* act = smem;
  const float* biasf = (const float*)(smem + 32*CHS);
  const int kg = lane>>4, col = lane&15;
  const int wc = wave&1;
  const int e0 = blockIdx.x*128;
  // gather msg_in = [h[src] | h[dst]] into act chunks (0..15 src, 16..31 dst)
  {
    const int* ids = (wave < 2) ? src_csr : dst_csr;
    const int row0 = ids[e0 + lane]      * NFEAT;
    const int row1 = ids[e0 + 64 + lane] * NFEAT;
    #pragma unroll
    for (int i=0;i<8;++i){
      int c = wave*8 + i;
      int f = (c&15)*8;
      load_lds16(h + row0 + f, act + (size_t)c*CHS);
      load_lds16(h + row1 + f, act + (size_t)c*CHS + 1024);
    }
  }
  // L1 K-step-0 B prefetch (global -> regs)
  half8 b[2][8];
  #pragma unroll
  for (int nt=0; nt<8; ++nt)
    b[0][nt] = *(const half8*)&W1s[(size_t)(kg*256 + wc*128 + nt*16 + col)*8];

  floatx4 acc[4][8];
  const floatx4 fz = {0.f,0.f,0.f,0.f};
  #pragma unroll
  for (int i=0;i<4;++i)
    #pragma unroll
    for (int j=0;j<8;++j) acc[i][j] = fz;

  WAITV0(); SBAR();                    // act (+bias at it=0) staged everywhere

  run_layer<256,256>(W1s, W2s, act, b, wave, lane, acc);
  WAITLGKM(); SBAR();
  epi_relu<8>(acc, biasf, 0, act, wave, lane);
  WAITLGKM(); SBAR();
  run_layer<256,256>(W2s, W3s, act, b, wave, lane, acc);
  WAITLGKM(); SBAR();
  epi_relu<8>(acc, biasf, 256, act, wave, lane);
  WAITLGKM(); SBAR();
  run_layer<256,128>(W3s, W4s, act, b, wave, lane, acc);
  WAITLGKM(); SBAR();
  epi_relu<8>(acc, biasf, 512, act, wave, lane);
  WAITLGKM(); SBAR();
  run_layer<128,0>(W4s, nullptr, act, b, wave, lane, acc);
  // L4 epilogue -> messages in CSR-slot order (contiguous rows), includes b4
  {
    const int rg = lane>>4;
    const int wr = wave>>1;
    const int r0 = wr*64;
    #pragma unroll
    for (int nt=0; nt<4; ++nt){
      int j = wc*64 + nt*16 + col;
      float bv = biasf[768 + j];
      #pragma unroll
      for (int mt=0; mt<4; ++mt){
        #pragma unroll
        for (int r=0; r<4; ++r){
          int e = e0 + r0 + mt*16 + rg*4 + r;
          messages[(size_t)e*NEDGE + j] = (_Float16)(acc[mt][nt][r] + bv);
        }
      }
    }
  }
}

// ---------------- gru phase: agg + GRU + out projection, 32 nodes/block, 4 waves ----------
__device__ __forceinline__ void gru_phase(
    const _Float16* __restrict__ messages, const int* __restrict__ rowptr,
    const _Float16* __restrict__ nin16,
    _Float16* __restrict__ h16, float* __restrict__ h32,
    const _Float16* __restrict__ Wihs, const _Float16* __restrict__ Whhs,
    const _Float16* __restrict__ Wfs,
    const float* __restrict__ b_ih, const float* __restrict__ b_hh,
    const float* __restrict__ b_f,
    float* __restrict__ out, char* smem, int t, int wave, int lane){
  _Float16* A1 = (_Float16*)smem;            // [24][32][8]: 0..15 agg, 16..23 nin (12KB)
  _Float16* A2 = (_Float16*)(smem + 12288);  // [16][32][8]: h rows, then h_new (8KB)
  const int kg = lane>>4, col = lane&15;
  const int n0 = blockIdx.x*32;
  {
    const int node = lane&31;
    // nin chunks 16..23: wave w stages chunks 16+2w,16+2w+1 in one 1KB gload_lds
    load_lds16(nin16 + (size_t)(n0+node)*NIN + (wave*2 + (lane>>5))*8,
               smem + 8192 + (size_t)wave*1024);
    // h chunks 0..15: wave w stages 4 chunks (2 gload_lds)
    #pragma unroll
    for (int ii=0; ii<2; ++ii){
      int cb = wave*4 + ii*2;
      load_lds16(h16 + (size_t)(n0+node)*NFEAT + (cb + (lane>>5))*8,
                 smem + 12288 + (size_t)cb*512);
    }
  }
  // agg: stream CSR-contiguous message rows -> A1 chunks 0..15
  {
    const int slot = t>>5, l4 = (t&31)*4;   // 8 row-slots x 32 feature-lanes
    #pragma unroll
    for (int rr=0; rr<4; ++rr){
      int nl = rr*8 + slot;
      int n = n0 + nl;
      int beg = rowptr[n], end = rowptr[n+1];
      float a0=0,a1=0,a2=0,a3=0;
      for (int idx=beg; idx<end; ++idx){
        half4 v = *(const half4*)(messages + (size_t)idx*NEDGE + l4);
        a0 += (float)v.x; a1 += (float)v.y; a2 += (float)v.z; a3 += (float)v.w;
      }
      half4 o; o.x=(_Float16)a0; o.y=(_Float16)a1; o.z=(_Float16)a2; o.w=(_Float16)a3;
      *(half4*)&A1[(size_t)((l4>>3)*32 + nl)*8 + (l4&7)] = o;
    }
  }
  floatx4 gi[3][2][2], gh[3][2][2];
  const floatx4 fz = {0.f,0.f,0.f,0.f};
  #pragma unroll
  for (int g=0; g<3; ++g)
    #pragma unroll
    for (int nt=0; nt<2; ++nt)
      #pragma unroll
      for (int mt=0; mt<2; ++mt){ gi[g][nt][mt]=fz; gh[g][nt][mt]=fz; }

  __syncthreads();   // staging (vmcnt) + agg ds_writes (lgkm) visible

  // wave w owns features w*32..w*32+31 (all 3 gates); B direct from L2
  #pragma unroll
  for (int kk=0; kk<6; ++kk){
    half8 a[2];
    #pragma unroll
    for (int mt=0;mt<2;++mt)
      a[mt] = *(const half8*)&A1[(((kk*4+kg)*32) + mt*16 + col)*8];
    #pragma unroll
    for (int g=0; g<3; ++g)
      #pragma unroll
      for (int nt=0; nt<2; ++nt){
        int j = g*128 + wave*32 + nt*16 + col;
        half8 b = *(const half8*)&Wihs[(size_t)((kk*4+kg)*384 + j)*8];
        #pragma unroll
        for (int mt=0;mt<2;++mt)
          gi[g][nt][mt] = MFMA16(a[mt], b, gi[g][nt][mt]);
      }
  }
  #pragma unroll
  for (int kk=0; kk<4; ++kk){
    half8 a[2];
    #pragma unroll
    for (int mt=0;mt<2;++mt)
      a[mt] = *(const half8*)&A2[(((kk*4+kg)*32) + mt*16 + col)*8];
    #pragma unroll
    for (int g=0; g<3; ++g)
      #pragma unroll
      for (int nt=0; nt<2; ++nt){
        int j = g*128 + wave*32 + nt*16 + col;
        half8 b = *(const half8*)&Whhs[(size_t)((kk*4+kg)*384 + j)*8];
        #pragma unroll
        for (int mt=0;mt<2;++mt)
          gh[g][nt][mt] = MFMA16(a[mt], b, gh[g][nt][mt]);
      }
  }
  __syncthreads();   // all A2 (h_old) reads done before overwrite

  #pragma unroll
  for (int nt=0; nt<2; ++nt){
    int jl = wave*32 + nt*16 + col;     // feature 0..127
    float bir=b_ih[jl], biz=b_ih[128+jl], bin_=b_ih[256+jl];
    float bhr=b_hh[jl], bhz=b_hh[128+jl], bhn=b_hh[256+jl];
    #pragma unroll
    for (int mt=0; mt<2; ++mt){
      #pragma unroll
      for (int r=0; r<4; ++r){
        int e = mt*16 + kg*4 + r;
        float ir = gi[0][nt][mt][r] + bir;
        float iz = gi[1][nt][mt][r] + biz;
        float inn= gi[2][nt][mt][r] + bin_;
        float hr = gh[0][nt][mt][r] + bhr;
        float hz = gh[1][nt][mt][r] + bhz;
        float hn = gh[2][nt][mt][r] + bhn;
        float rg2 = 1.f/(1.f+__expf(-(ir+hr)));
        float zg  = 1.f/(1.f+__expf(-(iz+hz)));
        float ng  = tanhf(inn + rg2*hn);
        size_t hidx = (size_t)(n0+e)*NFEAT + jl;
        float hnew = (1.f-zg)*ng + zg*h32[hidx];
        h32[hidx] = hnew;
        h16[hidx] = (_Float16)hnew;
        A2[(((jl>>3)*32) + e)*8 + (jl&7)] = (_Float16)hnew;
      }
    }
  }
  __syncthreads();

  // out = h_new @ W_f^T + b_f  (K=128, 64 cols; wave w owns cols w*16..+15)
  floatx4 facc[2] = {fz, fz};
  #pragma unroll
  for (int kk=0; kk<4; ++kk){
    half8 a[2];
    #pragma unroll
    for (int mt=0;mt<2;++mt)
      a[mt] = *(const half8*)&A2[(((kk*4+kg)*32) + mt*16 + col)*8];
    half8 b = *(const half8*)&Wfs[(size_t)((kk*4+kg)*64 + wave*16 + col)*8];
    #pragma unroll
    for (int mt=0;mt<2;++mt)
      facc[mt] = MFMA16(a[mt], b, facc[mt]);
  }
  float bf = b_f[wave*16+col];
  #pragma unroll
  for (int mt=0; mt<2; ++mt){
    #pragma unroll
    for (int r=0; r<4; ++r){
      int e = mt*16 + kg*4 + r;
      out[(size_t)(n0+e)*NOUTD + wave*16 + col] = facc[mt][r] + bf;
    }
  }
}

// ---------------- persistent fused kernel: 7 iterations, grid-barriered ----------------
__global__ __launch_bounds__(256,2) void fused_kernel(
    const _Float16* __restrict__ nin16,
    _Float16* __restrict__ h16, float* __restrict__ h32,
    _Float16* __restrict__ messages,
    const int* __restrict__ src_csr, const int* __restrict__ dst_csr,
    const int* __restrict__ rowptr,
    const _Float16* __restrict__ W1s, const _Float16* __restrict__ W2s,
    const _Float16* __restrict__ W3s, const _Float16* __restrict__ W4s,
    const float* __restrict__ msgbias,
    const _Float16* __restrict__ Wihs, const _Float16* __restrict__ Whhs,
    const _Float16* __restrict__ Wfs,
    const float* __restrict__ b_ih, const float* __restrict__ b_hh,
    const float* __restrict__ b_f,
    float* __restrict__ out, int* __restrict__ bar){
  __shared__ __align__(16) char smem[32*CHS + 4096];   // 70656 B -> exactly 2 blocks/CU
  const int t = threadIdx.x, wave = t>>6, lane = t&63;
  // stage msg bias once into high LDS (gru phase only touches first 20 KB)
  load_lds16((const char*)msgbias + wave*1024 + lane*16, smem + 32*CHS + wave*1024);

  for (int it=0; it<NITERS; ++it){
    msg_phase(h16, src_csr, dst_csr, W1s, W2s, W3s, W4s, messages, smem, wave, lane);
    gridbar(bar);                       // all messages visible device-wide
    gru_phase(messages, rowptr, nin16, h16, h32, Wihs, Whhs, Wfs,
              b_ih, b_hh, b_f, out + (size_t)it*N_NODES*NOUTD, smem, t, wave, lane);
    if (it < NITERS-1) gridbar(bar);    // h16/h32 visible for next msg phase
  }
}

// ---------------- launch ----------------
extern "C" void kernel_launch(void* const* d_in, const int* in_sizes, int n_in,
                              void* d_out, int out_size, void* d_ws, size_t ws_size,
                              hipStream_t stream){
  (void)in_sizes; (void)n_in; (void)out_size; (void)ws_size;
  const float* node_inputs = (const float*)d_in[0];
  const int*   src_ids = (const int*)d_in[1];
  const int*   dst_ids = (const int*)d_in[2];
  const float* W1 = (const float*)d_in[3];  const float* b1 = (const float*)d_in[4];
  const float* W2 = (const float*)d_in[5];  const float* b2 = (const float*)d_in[6];
  const float* W3 = (const float*)d_in[7];  const float* b3 = (const float*)d_in[8];
  const float* W4 = (const float*)d_in[9];  const float* b4 = (const float*)d_in[10];
  const float* W_ih = (const float*)d_in[11];
  const float* W_hh = (const float*)d_in[12];
  const float* b_ih = (const float*)d_in[13];
  const float* b_hh = (const float*)d_in[14];
  const float* W_f  = (const float*)d_in[15];
  const float* b_f  = (const float*)d_in[16];
  float* out = (float*)d_out;

  char* ws = (char*)d_ws;
  auto alloc = [&](size_t b){ char* p = ws; ws += (b + 255) & ~(size_t)255; return p; };
  _Float16* h16  = (_Float16*)alloc((size_t)N_NODES*NFEAT*2);
  float*    h32  = (float*)   alloc((size_t)N_NODES*NFEAT*4);
  _Float16* nin16= (_Float16*)alloc((size_t)N_NODES*NIN*2);
  _Float16* msgs = (_Float16*)alloc((size_t)N_EDGES*NEDGE*2);
  _Float16* W1s  = (_Float16*)alloc(256*256*2);
  _Float16* W2s  = (_Float16*)alloc(256*256*2);
  _Float16* W3s  = (_Float16*)alloc(256*256*2);
  _Float16* W4s  = (_Float16*)alloc(128*256*2);
  _Float16* Wihs = (_Float16*)alloc(384*192*2);
  _Float16* Whhs = (_Float16*)alloc(384*128*2);
  _Float16* Wfs  = (_Float16*)alloc(64*128*2);
  float* msgbias = (float*)alloc(1024*4);
  int* cnt     = (int*)alloc((size_t)N_NODES*4);
  int* rowptr  = (int*)alloc((size_t)(N_NODES+1)*4);
  int* offs    = (int*)alloc((size_t)N_NODES*4);
  int* src_csr = (int*)alloc((size_t)N_EDGES*4);
  int* dst_csr = (int*)alloc((size_t)N_EDGES*4);
  int* bar     = (int*)alloc(1024);

  setup_kernel<<<8192+4096+64+176+4,256,0,stream>>>(
      node_inputs, W1,W2,W3,W4, W_ih,W_hh,W_f, b1,b2,b3,b4,
      h32, h16, nin16, W1s,W2s,W3s,W4s, Wihs,Whhs,Wfs, msgbias, cnt);
  hist_kernel<<<N_EDGES/256,256,0,stream>>>(dst_ids, cnt);
  scan_kernel<<<1,1024,0,stream>>>(cnt, rowptr, offs, bar);
  scatter_kernel<<<N_EDGES/256,256,0,stream>>>(src_ids, dst_ids, offs, src_csr, dst_csr);

  fused_kernel<<<NBLKS,256,0,stream>>>(nin16, h16, h32, msgs, src_csr, dst_csr, rowptr,
                                       W1s, W2s, W3s, W4s, msgbias,
                                       Wihs, Whhs, Wfs, b_ih, b_hh, b_f, out, bar);
}

// Round 10
// 2185.173 us; speedup vs baseline: 1.7068x; 1.7068x over previous
//
#include <hip/hip_runtime.h>
#include <cstdint>
#include <cstddef>

#define N_NODES 16384
#define N_EDGES 65536
#define NFEAT 128   // GRU hidden
#define NIN   64    // node inputs
#define NEDGE 128   // edge features
#define NOUTD 64    // node outputs
#define NITERS 7
#define NBLKS 512   // persistent grid: exactly 2 blocks/CU x 256 CUs

#define CHS 2080    // act chunk stride bytes (128 edges * 16B + 32B pad)

typedef _Float16 half8 __attribute__((ext_vector_type(8)));
typedef _Float16 half4 __attribute__((ext_vector_type(4)));
typedef float floatx4 __attribute__((ext_vector_type(4)));

#define MFMA16(a,b,c) __builtin_amdgcn_mfma_f32_16x16x32_f16((a),(b),(c),0,0,0)

// raw barrier (no vmcnt(0) drain, unlike __syncthreads)
#define SBAR() asm volatile("s_barrier" ::: "memory")
#define WAITLGKM() asm volatile("s_waitcnt lgkmcnt(0)" ::: "memory")
#define WAITV0() asm volatile("s_waitcnt vmcnt(0)" ::: "memory")

// async global->LDS, 16B per lane. Global src per-lane; LDS dest wave-uniform base (+lane*16 by HW).
__device__ __forceinline__ void load_lds16(const void* g, void* l){
  __builtin_amdgcn_global_load_lds(
      (__attribute__((address_space(1))) void*)(uintptr_t)g,
      (__attribute__((address_space(3))) void*)l,
      16, 0, 0);
}

// ---------------- device-wide barrier (2-level, generation-based) ----------------
// bar[grp*16] grp<8: group arrival counters; bar[128]: root; bar[144]: generation.
// Exactly ONE buffer_wbl2 (release fetch_add) and ONE buffer_inv (acquire fence)
// per block per barrier. Spin loads are RELAXED (round-9 bug: ACQUIRE spin = one
// full L2 invalidate per poll -> 1.5 GB refetch, 8x regression).
__device__ __forceinline__ void gridbar(int* bar){
  __syncthreads();                 // drains each wave's stores (vmcnt0) before arrival
  if (threadIdx.x == 0){
    int g = __hip_atomic_load(&bar[144], __ATOMIC_RELAXED, __HIP_MEMORY_SCOPE_AGENT);
    int grp = blockIdx.x & 7;
    // release: one L2 writeback publishes this XCD's messages/h stores
    int a = __hip_atomic_fetch_add(&bar[grp*16], 1, __ATOMIC_RELEASE, __HIP_MEMORY_SCOPE_AGENT);
    if (a == (NBLKS/8 - 1)){
      __hip_atomic_store(&bar[grp*16], 0, __ATOMIC_RELAXED, __HIP_MEMORY_SCOPE_AGENT);
      int r = __hip_atomic_fetch_add(&bar[128], 1, __ATOMIC_RELAXED, __HIP_MEMORY_SCOPE_AGENT);
      if (r == 7){
        __hip_atomic_store(&bar[128], 0, __ATOMIC_RELAXED, __HIP_MEMORY_SCOPE_AGENT);
        __hip_atomic_store(&bar[144], g+1, __ATOMIC_RELAXED, __HIP_MEMORY_SCOPE_AGENT);
      } else {
        while (__hip_atomic_load(&bar[144], __ATOMIC_RELAXED, __HIP_MEMORY_SCOPE_AGENT) == g)
          __builtin_amdgcn_s_sleep(2);
      }
    } else {
      while (__hip_atomic_load(&bar[144], __ATOMIC_RELAXED, __HIP_MEMORY_SCOPE_AGENT) == g)
        __builtin_amdgcn_s_sleep(2);
    }
  }
  __syncthreads();
  // acquire: one L2/L1 invalidate so this block sees other XCDs' stores
  __builtin_amdgcn_fence(__ATOMIC_ACQUIRE, "agent");
}

// ---------------- one-shot setup: inits + fp16 weight repack + bias concat ----------------
__global__ void setup_kernel(
    const float* __restrict__ node_inputs,
    const float* __restrict__ W1, const float* __restrict__ W2,
    const float* __restrict__ W3, const float* __restrict__ W4,
    const float* __restrict__ W_ih, const float* __restrict__ W_hh,
    const float* __restrict__ W_f,
    const float* __restrict__ b1, const float* __restrict__ b2,
    const float* __restrict__ b3, const float* __restrict__ b4,
    float* __restrict__ h32, _Float16* __restrict__ h16,
    _Float16* __restrict__ nin16,
    _Float16* __restrict__ W1s, _Float16* __restrict__ W2s, _Float16* __restrict__ W3s,
    _Float16* __restrict__ W4s, _Float16* __restrict__ Wihs, _Float16* __restrict__ Whhs,
    _Float16* __restrict__ Wfs, float* __restrict__ msgbias, int* __restrict__ cnt){
  int b = blockIdx.x, t = threadIdx.x;
  if (b < 8192){ int i=b*256+t; h32[i]=0.f; h16[i]=(_Float16)0.f; return; }
  b -= 8192;
  if (b < 4096){ int i=b*256+t; nin16[i] = (_Float16)node_inputs[i]; return; }
  b -= 4096;
  if (b < 64){ cnt[b*256+t] = 0; return; }
  b -= 64;
  if (b >= 176){  // bias concat: b1|b2|b3|b4 -> msgbias[1024] (zero-padded)
    int i = (b-176)*256 + t;
    float v = 0.f;
    if      (i < 256) v = b1[i];
    else if (i < 512) v = b2[i-256];
    else if (i < 768) v = b3[i-512];
    else if (i < 896) v = b4[i-768];
    msgbias[i] = v; return;
  }
  const float* W; _Float16* o; int NO, KI, base;
  if      (b < 32){ W=W1;  o=W1s;  NO=256; KI=256; base=b; }
  else if (b < 64){ W=W2;  o=W2s;  NO=256; KI=256; base=b-32; }
  else if (b < 96){ W=W3;  o=W3s;  NO=256; KI=256; base=b-64; }
  else if (b <112){ W=W4;  o=W4s;  NO=128; KI=256; base=b-96; }
  else if (b <148){ W=W_ih;o=Wihs; NO=384; KI=192; base=b-112; }
  else if (b <172){ W=W_hh;o=Whhs; NO=384; KI=128; base=b-148; }
  else            { W=W_f; o=Wfs;  NO=64;  KI=128; base=b-172; }
  int g = base*256 + t;
  int total = NO*(KI>>3);
  if (g >= total) return;
  int c = g/NO, j = g - c*NO;
  #pragma unroll
  for (int i=0;i<8;++i) o[(size_t)g*8+i] = (_Float16)W[(size_t)j*KI + c*8 + i];
}

__global__ void hist_kernel(const int* __restrict__ dst, int* __restrict__ cnt){
  int e = blockIdx.x*256+threadIdx.x; if (e<N_EDGES) atomicAdd(&cnt[dst[e]],1);
}
__global__ __launch_bounds__(1024) void scan_kernel(const int* __restrict__ cnt,
                                                    int* __restrict__ rowptr,
                                                    int* __restrict__ offs,
                                                    int* __restrict__ bar){
  __shared__ int sd[1024];
  int t = threadIdx.x;
  if (t < 256) bar[t] = 0;          // init device-barrier state each call
  int c[16]; int s=0;
  #pragma unroll
  for (int k=0;k<16;++k){ c[k]=cnt[t*16+k]; s+=c[k]; }
  sd[t]=s; __syncthreads();
  for (int off=1; off<1024; off<<=1){
    int v = (t>=off)? sd[t-off]:0;
    __syncthreads();
    sd[t]+=v;
    __syncthreads();
  }
  int base = sd[t]-s; // exclusive prefix
  #pragma unroll
  for (int k=0;k<16;++k){ rowptr[t*16+k]=base; offs[t*16+k]=base; base+=c[k]; }
  if (t==0) rowptr[N_NODES]=N_EDGES;
}
// CSR permutation: src/dst ids in CSR-slot order -> msg writes message rows
// contiguously in dst-grouped order (agg reads sequentially).
__global__ void scatter_kernel(const int* __restrict__ src, const int* __restrict__ dst,
                               int* __restrict__ offs,
                               int* __restrict__ src_csr, int* __restrict__ dst_csr){
  int e = blockIdx.x*256+threadIdx.x;
  if (e<N_EDGES){
    int d = dst[e];
    int p = atomicAdd(&offs[d],1);
    src_csr[p] = src[e];
    dst_csr[p] = d;
  }
}

// ---------------- msg phase: fused 4-layer edge MLP, 128 edges/block, 4 waves ----------------
// act LDS: [32 chunks][128 edges][8 halfs], chunk stride CHS. A frags from LDS (2M x 2N waves).
// B frags: global(L2) -> VGPR, double-buffered one full K-step ahead. No in-loop barriers.
template<int N, int NEXTN>
__device__ __forceinline__ void run_layer(const _Float16* __restrict__ Ws,
                                          const _Float16* __restrict__ nextWs,
                                          const char* act, half8 (&b)[2][8],
                                          int wave, int lane, floatx4 (&acc)[4][8]){
  constexpr int NTW  = N/32;
  constexpr int NNTW = (NEXTN>0)? NEXTN/32 : 0;
  const int kg = lane>>4, col = lane&15;
  const int wr = wave>>1, wc = wave&1;          // 2M x 2N wave grid
  const int j0  = wc*(N/2);
  const int j0n = wc*(NEXTN/2);
  const int r0  = wr*64;
  #pragma unroll
  for (int kk=0; kk<8; ++kk){
    if (kk < 7){
      #pragma unroll
      for (int nt=0; nt<NTW; ++nt)
        b[(kk+1)&1][nt] = *(const half8*)&Ws[(size_t)(((kk+1)*4+kg)*N + j0 + nt*16 + col)*8];
    } else if constexpr (NEXTN > 0){
      #pragma unroll
      for (int nt=0; nt<NNTW; ++nt)
        b[0][nt] = *(const half8*)&nextWs[(size_t)(kg*NEXTN + j0n + nt*16 + col)*8];
    }
    half8 a[4];
    #pragma unroll
    for (int mt=0; mt<4; ++mt)
      a[mt] = *(const half8*)(act + (size_t)(kk*4+kg)*CHS + (r0 + mt*16 + col)*16);
    __builtin_amdgcn_s_setprio(1);
    #pragma unroll
    for (int nt=0; nt<NTW; ++nt)
      #pragma unroll
      for (int mt=0; mt<4; ++mt)
        acc[mt][nt] = MFMA16(a[mt], b[kk&1][nt], acc[mt][nt]);
    __builtin_amdgcn_s_setprio(0);
  }
}

template<int NTW>
__device__ __forceinline__ void epi_relu(floatx4 (&acc)[4][8], const float* __restrict__ biasf,
                                         int boff, char* act, int wave, int lane){
  const int rg = lane>>4, col = lane&15;
  const int wr = wave>>1, wc = wave&1;
  const int r0 = wr*64;
  #pragma unroll
  for (int nt=0; nt<NTW; ++nt){
    int j = wc*(NTW*16) + nt*16 + col;
    float bv = biasf[boff + j];        // LDS read (lgkm) -- keeps vmcnt clean
    char* dst = act + (size_t)(j>>3)*CHS + (j&7)*2;
    #pragma unroll
    for (int mt=0; mt<4; ++mt){
      #pragma unroll
      for (int r=0; r<4; ++r){
        int e = r0 + mt*16 + rg*4 + r;
        float v = fmaxf(acc[mt][nt][r] + bv, 0.f);
        acc[mt][nt][r] = 0.f;
        *(_Float16*)(dst + (size_t)e*16) = (_Float16)v;
      }
    }
  }
}

__device__ __forceinline__ void msg_phase(
    const _Float16* __restrict__ h,
    const int* __restrict__ src_csr, const int* __restrict__ dst_csr,
    const _Float16* __restrict__ W1s, const _Float16* __restrict__ W2s,
    const _Float16* __restrict__ W3s, const _Float16* __restrict__ W4s,
    _Float16* __restrict__ messages,
    char* smem, int wave, int lane){
  char* act = smem;
  const float* biasf = (const float*)(smem + 32*CHS);
  const int kg = lane>>4, col = lane&15;
  const int wc = wave&1;
  const int e0 = blockIdx.x*128;
  // gather msg_in = [h[src] | h[dst]] into act chunks (0..15 src, 16..31 dst)
  {
    const int* ids = (wave < 2) ? src_csr : dst_csr;
    const int row0 = ids[e0 + lane]      * NFEAT;
    const int row1 = ids[e0 + 64 + lane] * NFEAT;
    #pragma unroll
    for (int i=0;i<8;++i){
      int c = wave*8 + i;
      int f = (c&15)*8;
      load_lds16(h + row0 + f, act + (size_t)c*CHS);
      load_lds16(h + row1 + f, act + (size_t)c*CHS + 1024);
    }
  }
  // L1 K-step-0 B prefetch (global -> regs)
  half8 b[2][8];
  #pragma unroll
  for (int nt=0; nt<8; ++nt)
    b[0][nt] = *(const half8*)&W1s[(size_t)(kg*256 + wc*128 + nt*16 + col)*8];

  floatx4 acc[4][8];
  const floatx4 fz = {0.f,0.f,0.f,0.f};
  #pragma unroll
  for (int i=0;i<4;++i)
    #pragma unroll
    for (int j=0;j<8;++j) acc[i][j] = fz;

  WAITV0(); SBAR();                    // act (+bias at it=0) staged everywhere

  run_layer<256,256>(W1s, W2s, act, b, wave, lane, acc);
  WAITLGKM(); SBAR();
  epi_relu<8>(acc, biasf, 0, act, wave, lane);
  WAITLGKM(); SBAR();
  run_layer<256,256>(W2s, W3s, act, b, wave, lane, acc);
  WAITLGKM(); SBAR();
  epi_relu<8>(acc, biasf, 256, act, wave, lane);
  WAITLGKM(); SBAR();
  run_layer<256,128>(W3s, W4s, act, b, wave, lane, acc);
  WAITLGKM(); SBAR();
  epi_relu<8>(acc, biasf, 512, act, wave, lane);
  WAITLGKM(); SBAR();
  run_layer<128,0>(W4s, nullptr, act, b, wave, lane, acc);
  // L4 epilogue -> messages in CSR-slot order (contiguous rows), includes b4
  {
    const int rg = lane>>4;
    const int wr = wave>>1;
    const int r0 = wr*64;
    #pragma unroll
    for (int nt=0; nt<4; ++nt){
      int j = wc*64 + nt*16 + col;
      float bv = biasf[768 + j];
      #pragma unroll
      for (int mt=0; mt<4; ++mt){
        #pragma unroll
        for (int r=0; r<4; ++r){
          int e = e0 + r0 + mt*16 + rg*4 + r;
          messages[(size_t)e*NEDGE + j] = (_Float16)(acc[mt][nt][r] + bv);
        }
      }
    }
  }
}

// ---------------- gru phase: agg + GRU + out projection, 32 nodes/block, 4 waves ----------
__device__ __forceinline__ void gru_phase(
    const _Float16* __restrict__ messages, const int* __restrict__ rowptr,
    const _Float16* __restrict__ nin16,
    _Float16* __restrict__ h16, float* __restrict__ h32,
    const _Float16* __restrict__ Wihs, const _Float16* __restrict__ Whhs,
    const _Float16* __restrict__ Wfs,
    const float* __restrict__ b_ih, const float* __restrict__ b_hh,
    const float* __restrict__ b_f,
    float* __restrict__ out, char* smem, int t, int wave, int lane){
  _Float16* A1 = (_Float16*)smem;            // [24][32][8]: 0..15 agg, 16..23 nin (12KB)
  _Float16* A2 = (_Float16*)(smem + 12288);  // [16][32][8]: h rows, then h_new (8KB)
  const int kg = lane>>4, col = lane&15;
  const int n0 = blockIdx.x*32;
  {
    const int node = lane&31;
    // nin chunks 16..23: wave w stages chunks 16+2w,16+2w+1 in one 1KB gload_lds
    load_lds16(nin16 + (size_t)(n0+node)*NIN + (wave*2 + (lane>>5))*8,
               smem + 8192 + (size_t)wave*1024);
    // h chunks 0..15: wave w stages 4 chunks (2 gload_lds)
    #pragma unroll
    for (int ii=0; ii<2; ++ii){
      int cb = wave*4 + ii*2;
      load_lds16(h16 + (size_t)(n0+node)*NFEAT + (cb + (lane>>5))*8,
                 smem + 12288 + (size_t)cb*512);
    }
  }
  // agg: stream CSR-contiguous message rows -> A1 chunks 0..15
  {
    const int slot = t>>5, l4 = (t&31)*4;   // 8 row-slots x 32 feature-lanes
    #pragma unroll
    for (int rr=0; rr<4; ++rr){
      int nl = rr*8 + slot;
      int n = n0 + nl;
      int beg = rowptr[n], end = rowptr[n+1];
      float a0=0,a1=0,a2=0,a3=0;
      for (int idx=beg; idx<end; ++idx){
        half4 v = *(const half4*)(messages + (size_t)idx*NEDGE + l4);
        a0 += (float)v.x; a1 += (float)v.y; a2 += (float)v.z; a3 += (float)v.w;
      }
      half4 o; o.x=(_Float16)a0; o.y=(_Float16)a1; o.z=(_Float16)a2; o.w=(_Float16)a3;
      *(half4*)&A1[(size_t)((l4>>3)*32 + nl)*8 + (l4&7)] = o;
    }
  }
  floatx4 gi[3][2][2], gh[3][2][2];
  const floatx4 fz = {0.f,0.f,0.f,0.f};
  #pragma unroll
  for (int g=0; g<3; ++g)
    #pragma unroll
    for (int nt=0; nt<2; ++nt)
      #pragma unroll
      for (int mt=0; mt<2; ++mt){ gi[g][nt][mt]=fz; gh[g][nt][mt]=fz; }

  __syncthreads();   // staging (vmcnt) + agg ds_writes (lgkm) visible

  // wave w owns features w*32..w*32+31 (all 3 gates); B direct from L2
  #pragma unroll
  for (int kk=0; kk<6; ++kk){
    half8 a[2];
    #pragma unroll
    for (int mt=0;mt<2;++mt)
      a[mt] = *(const half8*)&A1[(((kk*4+kg)*32) + mt*16 + col)*8];
    #pragma unroll
    for (int g=0; g<3; ++g)
      #pragma unroll
      for (int nt=0; nt<2; ++nt){
        int j = g*128 + wave*32 + nt*16 + col;
        half8 b = *(const half8*)&Wihs[(size_t)((kk*4+kg)*384 + j)*8];
        #pragma unroll
        for (int mt=0;mt<2;++mt)
          gi[g][nt][mt] = MFMA16(a[mt], b, gi[g][nt][mt]);
      }
  }
  #pragma unroll
  for (int kk=0; kk<4; ++kk){
    half8 a[2];
    #pragma unroll
    for (int mt=0;mt<2;++mt)
      a[mt] = *(const half8*)&A2[(((kk*4+kg)*32) + mt*16 + col)*8];
    #pragma unroll
    for (int g=0; g<3; ++g)
      #pragma unroll
      for (int nt=0; nt<2; ++nt){
        int j = g*128 + wave*32 + nt*16 + col;
        half8 b = *(const half8*)&Whhs[(size_t)((kk*4+kg)*384 + j)*8];
        #pragma unroll
        for (int mt=0;mt<2;++mt)
          gh[g][nt][mt] = MFMA16(a[mt], b, gh[g][nt][mt]);
      }
  }
  __syncthreads();   // all A2 (h_old) reads done before overwrite

  #pragma unroll
  for (int nt=0; nt<2; ++nt){
    int jl = wave*32 + nt*16 + col;     // feature 0..127
    float bir=b_ih[jl], biz=b_ih[128+jl], bin_=b_ih[256+jl];
    float bhr=b_hh[jl], bhz=b_hh[128+jl], bhn=b_hh[256+jl];
    #pragma unroll
    for (int mt=0; mt<2; ++mt){
      #pragma unroll
      for (int r=0; r<4; ++r){
        int e = mt*16 + kg*4 + r;
        float ir = gi[0][nt][mt][r] + bir;
        float iz = gi[1][nt][mt][r] + biz;
        float inn= gi[2][nt][mt][r] + bin_;
        float hr = gh[0][nt][mt][r] + bhr;
        float hz = gh[1][nt][mt][r] + bhz;
        float hn = gh[2][nt][mt][r] + bhn;
        float rg2 = 1.f/(1.f+__expf(-(ir+hr)));
        float zg  = 1.f/(1.f+__expf(-(iz+hz)));
        float ng  = tanhf(inn + rg2*hn);
        size_t hidx = (size_t)(n0+e)*NFEAT + jl;
        float hnew = (1.f-zg)*ng + zg*h32[hidx];
        h32[hidx] = hnew;
        h16[hidx] = (_Float16)hnew;
        A2[(((jl>>3)*32) + e)*8 + (jl&7)] = (_Float16)hnew;
      }
    }
  }
  __syncthreads();

  // out = h_new @ W_f^T + b_f  (K=128, 64 cols; wave w owns cols w*16..+15)
  floatx4 facc[2] = {fz, fz};
  #pragma unroll
  for (int kk=0; kk<4; ++kk){
    half8 a[2];
    #pragma unroll
    for (int mt=0;mt<2;++mt)
      a[mt] = *(const half8*)&A2[(((kk*4+kg)*32) + mt*16 + col)*8];
    half8 b = *(const half8*)&Wfs[(size_t)((kk*4+kg)*64 + wave*16 + col)*8];
    #pragma unroll
    for (int mt=0;mt<2;++mt)
      facc[mt] = MFMA16(a[mt], b, facc[mt]);
  }
  float bf = b_f[wave*16+col];
  #pragma unroll
  for (int mt=0; mt<2; ++mt){
    #pragma unroll
    for (int r=0; r<4; ++r){
      int e = mt*16 + kg*4 + r;
      out[(size_t)(n0+e)*NOUTD + wave*16 + col] = facc[mt][r] + bf;
    }
  }
}

// ---------------- persistent fused kernel: 7 iterations, grid-barriered ----------------
__global__ __launch_bounds__(256,2) void fused_kernel(
    const _Float16* __restrict__ nin16,
    _Float16* __restrict__ h16, float* __restrict__ h32,
    _Float16* __restrict__ messages,
    const int* __restrict__ src_csr, const int* __restrict__ dst_csr,
    const int* __restrict__ rowptr,
    const _Float16* __restrict__ W1s, const _Float16* __restrict__ W2s,
    const _Float16* __restrict__ W3s, const _Float16* __restrict__ W4s,
    const float* __restrict__ msgbias,
    const _Float16* __restrict__ Wihs, const _Float16* __restrict__ Whhs,
    const _Float16* __restrict__ Wfs,
    const float* __restrict__ b_ih, const float* __restrict__ b_hh,
    const float* __restrict__ b_f,
    float* __restrict__ out, int* __restrict__ bar){
  __shared__ __align__(16) char smem[32*CHS + 4096];   // 70656 B -> exactly 2 blocks/CU
  const int t = threadIdx.x, wave = t>>6, lane = t&63;
  // stage msg bias once into high LDS (gru phase only touches first 20 KB)
  load_lds16((const char*)msgbias + wave*1024 + lane*16, smem + 32*CHS + wave*1024);

  for (int it=0; it<NITERS; ++it){
    msg_phase(h16, src_csr, dst_csr, W1s, W2s, W3s, W4s, messages, smem, wave, lane);
    gridbar(bar);                       // all messages visible device-wide
    gru_phase(messages, rowptr, nin16, h16, h32, Wihs, Whhs, Wfs,
              b_ih, b_hh, b_f, out + (size_t)it*N_NODES*NOUTD, smem, t, wave, lane);
    if (it < NITERS-1) gridbar(bar);    // h16/h32 visible for next msg phase
  }
}

// ---------------- launch ----------------
extern "C" void kernel_launch(void* const* d_in, const int* in_sizes, int n_in,
                              void* d_out, int out_size, void* d_ws, size_t ws_size,
                              hipStream_t stream){
  (void)in_sizes; (void)n_in; (void)out_size; (void)ws_size;
  const float* node_inputs = (const float*)d_in[0];
  const int*   src_ids = (const int*)d_in[1];
  const int*   dst_ids = (const int*)d_in[2];
  const float* W1 = (const float*)d_in[3];  const float* b1 = (const float*)d_in[4];
  const float* W2 = (const float*)d_in[5];  const float* b2 = (const float*)d_in[6];
  const float* W3 = (const float*)d_in[7];  const float* b3 = (const float*)d_in[8];
  const float* W4 = (const float*)d_in[9];  const float* b4 = (const float*)d_in[10];
  const float* W_ih = (const float*)d_in[11];
  const float* W_hh = (const float*)d_in[12];
  const float* b_ih = (const float*)d_in[13];
  const float* b_hh = (const float*)d_in[14];
  const float* W_f  = (const float*)d_in[15];
  const float* b_f  = (const float*)d_in[16];
  float* out = (float*)d_out;

  char* ws = (char*)d_ws;
  auto alloc = [&](size_t b){ char* p = ws; ws += (b + 255) & ~(size_t)255; return p; };
  _Float16* h16  = (_Float16*)alloc((size_t)N_NODES*NFEAT*2);
  float*    h32  = (float*)   alloc((size_t)N_NODES*NFEAT*4);
  _Float16* nin16= (_Float16*)alloc((size_t)N_NODES*NIN*2);
  _Float16* msgs = (_Float16*)alloc((size_t)N_EDGES*NEDGE*2);
  _Float16* W1s  = (_Float16*)alloc(256*256*2);
  _Float16* W2s  = (_Float16*)alloc(256*256*2);
  _Float16* W3s  = (_Float16*)alloc(256*256*2);
  _Float16* W4s  = (_Float16*)alloc(128*256*2);
  _Float16* Wihs = (_Float16*)alloc(384*192*2);
  _Float16* Whhs = (_Float16*)alloc(384*128*2);
  _Float16* Wfs  = (_Float16*)alloc(64*128*2);
  float* msgbias = (float*)alloc(1024*4);
  int* cnt     = (int*)alloc((size_t)N_NODES*4);
  int* rowptr  = (int*)alloc((size_t)(N_NODES+1)*4);
  int* offs    = (int*)alloc((size_t)N_NODES*4);
  int* src_csr = (int*)alloc((size_t)N_EDGES*4);
  int* dst_csr = (int*)alloc((size_t)N_EDGES*4);
  int* bar     = (int*)alloc(1024);

  setup_kernel<<<8192+4096+64+176+4,256,0,stream>>>(
      node_inputs, W1,W2,W3,W4, W_ih,W_hh,W_f, b1,b2,b3,b4,
      h32, h16, nin16, W1s,W2s,W3s,W4s, Wihs,Whhs,Wfs, msgbias, cnt);
  hist_kernel<<<N_EDGES/256,256,0,stream>>>(dst_ids, cnt);
  scan_kernel<<<1,1024,0,stream>>>(cnt, rowptr, offs, bar);
  scatter_kernel<<<N_EDGES/256,256,0,stream>>>(src_ids, dst_ids, offs, src_csr, dst_csr);

  fused_kernel<<<NBLKS,256,0,stream>>>(nin16, h16, h32, msgs, src_csr, dst_csr, rowptr,
                                       W1s, W2s, W3s, W4s, msgbias,
                                       Wihs, Whhs, Wfs, b_ih, b_hh, b_f, out, bar);
}

// Round 11
// 2019.012 us; speedup vs baseline: 1.8473x; 1.0823x over previous
//
#include <hip/hip_runtime.h>
#include <cstdint>
#include <cstddef>

#define N_NODES 16384
#define N_EDGES 65536
#define NFEAT 128   // GRU hidden
#define NIN   64    // node inputs
#define NEDGE 128   // edge features
#define NOUTD 64    // node outputs
#define NITERS 7
#define NBLKS 512   // persistent grid: exactly 2 blocks/CU x 256 CUs

#define CHS 2080    // act chunk stride bytes (128 edges * 16B + 32B pad)

typedef _Float16 half8 __attribute__((ext_vector_type(8)));
typedef _Float16 half4 __attribute__((ext_vector_type(4)));
typedef float floatx4 __attribute__((ext_vector_type(4)));

#define MFMA16(a,b,c) __builtin_amdgcn_mfma_f32_16x16x32_f16((a),(b),(c),0,0,0)

// raw barrier (no vmcnt(0) drain, unlike __syncthreads)
#define SBAR() asm volatile("s_barrier" ::: "memory")
#define WAITLGKM() asm volatile("s_waitcnt lgkmcnt(0)" ::: "memory")
#define WAITV0() asm volatile("s_waitcnt vmcnt(0)" ::: "memory")

// async global->LDS, 16B per lane. Global src per-lane; LDS dest wave-uniform base (+lane*16 by HW).
__device__ __forceinline__ void load_lds16(const void* g, void* l){
  __builtin_amdgcn_global_load_lds(
      (__attribute__((address_space(1))) void*)(uintptr_t)g,
      (__attribute__((address_space(3))) void*)l,
      16, 0, 0);
}

// ---------------- device-wide barrier (2-level, generation-based) ----------------
// NO acquire fence / buffer_inv anywhere (rounds 9/10: per-block inv wiped the
// L2-resident weights 6656x -> 1.5 GB refetch). Coherence instead comes from
// write-once-per-launch communication buffers (messages[it], h16[it]): a reader
// can never hold a stale copy of a line that is only written once before it reads.
// Writer side: RELEASE fetch_add = one buffer_wbl2 (writeback, L2 stays VALID).
__device__ __forceinline__ void gridbar(int* bar){
  __syncthreads();                 // drains each wave's stores (vmcnt0) before arrival
  if (threadIdx.x == 0){
    int g = __hip_atomic_load(&bar[144], __ATOMIC_RELAXED, __HIP_MEMORY_SCOPE_AGENT);
    int grp = blockIdx.x & 7;
    // release: one L2 writeback publishes this XCD's messages/h stores to L3
    int a = __hip_atomic_fetch_add(&bar[grp*16], 1, __ATOMIC_RELEASE, __HIP_MEMORY_SCOPE_AGENT);
    if (a == (NBLKS/8 - 1)){
      __hip_atomic_store(&bar[grp*16], 0, __ATOMIC_RELAXED, __HIP_MEMORY_SCOPE_AGENT);
      int r = __hip_atomic_fetch_add(&bar[128], 1, __ATOMIC_RELAXED, __HIP_MEMORY_SCOPE_AGENT);
      if (r == 7){
        __hip_atomic_store(&bar[128], 0, __ATOMIC_RELAXED, __HIP_MEMORY_SCOPE_AGENT);
        __hip_atomic_store(&bar[144], g+1, __ATOMIC_RELAXED, __HIP_MEMORY_SCOPE_AGENT);
      } else {
        while (__hip_atomic_load(&bar[144], __ATOMIC_RELAXED, __HIP_MEMORY_SCOPE_AGENT) == g)
          __builtin_amdgcn_s_sleep(2);
      }
    } else {
      while (__hip_atomic_load(&bar[144], __ATOMIC_RELAXED, __HIP_MEMORY_SCOPE_AGENT) == g)
        __builtin_amdgcn_s_sleep(2);
    }
  }
  __syncthreads();
}

// ---------------- one-shot setup: inits + fp16 weight repack + bias concat ----------------
__global__ void setup_kernel(
    const float* __restrict__ node_inputs,
    const float* __restrict__ W1, const float* __restrict__ W2,
    const float* __restrict__ W3, const float* __restrict__ W4,
    const float* __restrict__ W_ih, const float* __restrict__ W_hh,
    const float* __restrict__ W_f,
    const float* __restrict__ b1, const float* __restrict__ b2,
    const float* __restrict__ b3, const float* __restrict__ b4,
    float* __restrict__ h32, _Float16* __restrict__ h16,
    _Float16* __restrict__ nin16,
    _Float16* __restrict__ W1s, _Float16* __restrict__ W2s, _Float16* __restrict__ W3s,
    _Float16* __restrict__ W4s, _Float16* __restrict__ Wihs, _Float16* __restrict__ Whhs,
    _Float16* __restrict__ Wfs, float* __restrict__ msgbias, int* __restrict__ cnt){
  int b = blockIdx.x, t = threadIdx.x;
  if (b < 8192){ int i=b*256+t; h32[i]=0.f; h16[i]=(_Float16)0.f; return; }
  b -= 8192;
  if (b < 4096){ int i=b*256+t; nin16[i] = (_Float16)node_inputs[i]; return; }
  b -= 4096;
  if (b < 64){ cnt[b*256+t] = 0; return; }
  b -= 64;
  if (b >= 176){  // bias concat: b1|b2|b3|b4 -> msgbias[1024] (zero-padded)
    int i = (b-176)*256 + t;
    float v = 0.f;
    if      (i < 256) v = b1[i];
    else if (i < 512) v = b2[i-256];
    else if (i < 768) v = b3[i-512];
    else if (i < 896) v = b4[i-768];
    msgbias[i] = v; return;
  }
  const float* W; _Float16* o; int NO, KI, base;
  if      (b < 32){ W=W1;  o=W1s;  NO=256; KI=256; base=b; }
  else if (b < 64){ W=W2;  o=W2s;  NO=256; KI=256; base=b-32; }
  else if (b < 96){ W=W3;  o=W3s;  NO=256; KI=256; base=b-64; }
  else if (b <112){ W=W4;  o=W4s;  NO=128; KI=256; base=b-96; }
  else if (b <148){ W=W_ih;o=Wihs; NO=384; KI=192; base=b-112; }
  else if (b <172){ W=W_hh;o=Whhs; NO=384; KI=128; base=b-148; }
  else            { W=W_f; o=Wfs;  NO=64;  KI=128; base=b-172; }
  int g = base*256 + t;
  int total = NO*(KI>>3);
  if (g >= total) return;
  int c = g/NO, j = g - c*NO;
  #pragma unroll
  for (int i=0;i<8;++i) o[(size_t)g*8+i] = (_Float16)W[(size_t)j*KI + c*8 + i];
}

__global__ void hist_kernel(const int* __restrict__ dst, int* __restrict__ cnt){
  int e = blockIdx.x*256+threadIdx.x; if (e<N_EDGES) atomicAdd(&cnt[dst[e]],1);
}
__global__ __launch_bounds__(1024) void scan_kernel(const int* __restrict__ cnt,
                                                    int* __restrict__ rowptr,
                                                    int* __restrict__ offs,
                                                    int* __restrict__ bar){
  __shared__ int sd[1024];
  int t = threadIdx.x;
  if (t < 256) bar[t] = 0;          // init device-barrier state each call
  int c[16]; int s=0;
  #pragma unroll
  for (int k=0;k<16;++k){ c[k]=cnt[t*16+k]; s+=c[k]; }
  sd[t]=s; __syncthreads();
  for (int off=1; off<1024; off<<=1){
    int v = (t>=off)? sd[t-off]:0;
    __syncthreads();
    sd[t]+=v;
    __syncthreads();
  }
  int base = sd[t]-s; // exclusive prefix
  #pragma unroll
  for (int k=0;k<16;++k){ rowptr[t*16+k]=base; offs[t*16+k]=base; base+=c[k]; }
  if (t==0) rowptr[N_NODES]=N_EDGES;
}
// CSR permutation: src/dst ids in CSR-slot order -> msg writes message rows
// contiguously in dst-grouped order (agg reads sequentially).
__global__ void scatter_kernel(const int* __restrict__ src, const int* __restrict__ dst,
                               int* __restrict__ offs,
                               int* __restrict__ src_csr, int* __restrict__ dst_csr){
  int e = blockIdx.x*256+threadIdx.x;
  if (e<N_EDGES){
    int d = dst[e];
    int p = atomicAdd(&offs[d],1);
    src_csr[p] = src[e];
    dst_csr[p] = d;
  }
}

// ---------------- msg phase: fused 4-layer edge MLP, 128 edges/block, 4 waves ----------------
template<int N, int NEXTN>
__device__ __forceinline__ void run_layer(const _Float16* __restrict__ Ws,
                                          const _Float16* __restrict__ nextWs,
                                          const char* act, half8 (&b)[2][8],
                                          int wave, int lane, floatx4 (&acc)[4][8]){
  constexpr int NTW  = N/32;
  constexpr int NNTW = (NEXTN>0)? NEXTN/32 : 0;
  const int kg = lane>>4, col = lane&15;
  const int wr = wave>>1, wc = wave&1;          // 2M x 2N wave grid
  const int j0  = wc*(N/2);
  const int j0n = wc*(NEXTN/2);
  const int r0  = wr*64;
  #pragma unroll
  for (int kk=0; kk<8; ++kk){
    if (kk < 7){
      #pragma unroll
      for (int nt=0; nt<NTW; ++nt)
        b[(kk+1)&1][nt] = *(const half8*)&Ws[(size_t)(((kk+1)*4+kg)*N + j0 + nt*16 + col)*8];
    } else if constexpr (NEXTN > 0){
      #pragma unroll
      for (int nt=0; nt<NNTW; ++nt)
        b[0][nt] = *(const half8*)&nextWs[(size_t)(kg*NEXTN + j0n + nt*16 + col)*8];
    }
    half8 a[4];
    #pragma unroll
    for (int mt=0; mt<4; ++mt)
      a[mt] = *(const half8*)(act + (size_t)(kk*4+kg)*CHS + (r0 + mt*16 + col)*16);
    __builtin_amdgcn_s_setprio(1);
    #pragma unroll
    for (int nt=0; nt<NTW; ++nt)
      #pragma unroll
      for (int mt=0; mt<4; ++mt)
        acc[mt][nt] = MFMA16(a[mt], b[kk&1][nt], acc[mt][nt]);
    __builtin_amdgcn_s_setprio(0);
  }
}

template<int NTW>
__device__ __forceinline__ void epi_relu(floatx4 (&acc)[4][8], const float* __restrict__ biasf,
                                         int boff, char* act, int wave, int lane){
  const int rg = lane>>4, col = lane&15;
  const int wr = wave>>1, wc = wave&1;
  const int r0 = wr*64;
  #pragma unroll
  for (int nt=0; nt<NTW; ++nt){
    int j = wc*(NTW*16) + nt*16 + col;
    float bv = biasf[boff + j];        // LDS read (lgkm) -- keeps vmcnt clean
    char* dst = act + (size_t)(j>>3)*CHS + (j&7)*2;
    #pragma unroll
    for (int mt=0; mt<4; ++mt){
      #pragma unroll
      for (int r=0; r<4; ++r){
        int e = r0 + mt*16 + rg*4 + r;
        float v = fmaxf(acc[mt][nt][r] + bv, 0.f);
        acc[mt][nt][r] = 0.f;
        *(_Float16*)(dst + (size_t)e*16) = (_Float16)v;
      }
    }
  }
}

__device__ __forceinline__ void msg_phase(
    const _Float16* __restrict__ h,
    const int* __restrict__ src_csr, const int* __restrict__ dst_csr,
    const _Float16* __restrict__ W1s, const _Float16* __restrict__ W2s,
    const _Float16* __restrict__ W3s, const _Float16* __restrict__ W4s,
    _Float16* __restrict__ messages,
    char* smem, int wave, int lane){
  char* act = smem;
  const float* biasf = (const float*)(smem + 32*CHS);
  const int kg = lane>>4, col = lane&15;
  const int wc = wave&1;
  const int e0 = blockIdx.x*128;
  // gather msg_in = [h[src] | h[dst]] into act chunks (0..15 src, 16..31 dst)
  {
    const int* ids = (wave < 2) ? src_csr : dst_csr;
    const int row0 = ids[e0 + lane]      * NFEAT;
    const int row1 = ids[e0 + 64 + lane] * NFEAT;
    #pragma unroll
    for (int i=0;i<8;++i){
      int c = wave*8 + i;
      int f = (c&15)*8;
      load_lds16(h + row0 + f, act + (size_t)c*CHS);
      load_lds16(h + row1 + f, act + (size_t)c*CHS + 1024);
    }
  }
  // L1 K-step-0 B prefetch (global -> regs)
  half8 b[2][8];
  #pragma unroll
  for (int nt=0; nt<8; ++nt)
    b[0][nt] = *(const half8*)&W1s[(size_t)(kg*256 + wc*128 + nt*16 + col)*8];

  floatx4 acc[4][8];
  const floatx4 fz = {0.f,0.f,0.f,0.f};
  #pragma unroll
  for (int i=0;i<4;++i)
    #pragma unroll
    for (int j=0;j<8;++j) acc[i][j] = fz;

  WAITV0(); SBAR();                    // act (+bias at it=0) staged everywhere

  run_layer<256,256>(W1s, W2s, act, b, wave, lane, acc);
  WAITLGKM(); SBAR();
  epi_relu<8>(acc, biasf, 0, act, wave, lane);
  WAITLGKM(); SBAR();
  run_layer<256,256>(W2s, W3s, act, b, wave, lane, acc);
  WAITLGKM(); SBAR();
  epi_relu<8>(acc, biasf, 256, act, wave, lane);
  WAITLGKM(); SBAR();
  run_layer<256,128>(W3s, W4s, act, b, wave, lane, acc);
  WAITLGKM(); SBAR();
  epi_relu<8>(acc, biasf, 512, act, wave, lane);
  WAITLGKM(); SBAR();
  run_layer<128,0>(W4s, nullptr, act, b, wave, lane, acc);
  // L4 epilogue -> messages in CSR-slot order (contiguous rows), includes b4
  {
    const int rg = lane>>4;
    const int wr = wave>>1;
    const int r0 = wr*64;
    #pragma unroll
    for (int nt=0; nt<4; ++nt){
      int j = wc*64 + nt*16 + col;
      float bv = biasf[768 + j];
      #pragma unroll
      for (int mt=0; mt<4; ++mt){
        #pragma unroll
        for (int r=0; r<4; ++r){
          int e = e0 + r0 + mt*16 + rg*4 + r;
          messages[(size_t)e*NEDGE + j] = (_Float16)(acc[mt][nt][r] + bv);
        }
      }
    }
  }
}

// ---------------- gru phase: agg + GRU + out projection, 32 nodes/block, 4 waves ----------
__device__ __forceinline__ void gru_phase(
    const _Float16* __restrict__ messages, const int* __restrict__ rowptr,
    const _Float16* __restrict__ nin16,
    const _Float16* __restrict__ h_in, _Float16* __restrict__ h_out,
    float* __restrict__ h32,
    const _Float16* __restrict__ Wihs, const _Float16* __restrict__ Whhs,
    const _Float16* __restrict__ Wfs,
    const float* __restrict__ b_ih, const float* __restrict__ b_hh,
    const float* __restrict__ b_f,
    float* __restrict__ out, char* smem, int t, int wave, int lane){
  _Float16* A1 = (_Float16*)smem;            // [24][32][8]: 0..15 agg, 16..23 nin (12KB)
  _Float16* A2 = (_Float16*)(smem + 12288);  // [16][32][8]: h rows, then h_new (8KB)
  const int kg = lane>>4, col = lane&15;
  const int n0 = blockIdx.x*32;
  {
    const int node = lane&31;
    load_lds16(nin16 + (size_t)(n0+node)*NIN + (wave*2 + (lane>>5))*8,
               smem + 8192 + (size_t)wave*1024);
    #pragma unroll
    for (int ii=0; ii<2; ++ii){
      int cb = wave*4 + ii*2;
      load_lds16(h_in + (size_t)(n0+node)*NFEAT + (cb + (lane>>5))*8,
                 smem + 12288 + (size_t)cb*512);
    }
  }
  // agg: stream CSR-contiguous message rows -> A1 chunks 0..15
  {
    const int slot = t>>5, l4 = (t&31)*4;   // 8 row-slots x 32 feature-lanes
    #pragma unroll
    for (int rr=0; rr<4; ++rr){
      int nl = rr*8 + slot;
      int n = n0 + nl;
      int beg = rowptr[n], end = rowptr[n+1];
      float a0=0,a1=0,a2=0,a3=0;
      for (int idx=beg; idx<end; ++idx){
        half4 v = *(const half4*)(messages + (size_t)idx*NEDGE + l4);
        a0 += (float)v.x; a1 += (float)v.y; a2 += (float)v.z; a3 += (float)v.w;
      }
      half4 o; o.x=(_Float16)a0; o.y=(_Float16)a1; o.z=(_Float16)a2; o.w=(_Float16)a3;
      *(half4*)&A1[(size_t)((l4>>3)*32 + nl)*8 + (l4&7)] = o;
    }
  }
  floatx4 gi[3][2][2], gh[3][2][2];
  const floatx4 fz = {0.f,0.f,0.f,0.f};
  #pragma unroll
  for (int g=0; g<3; ++g)
    #pragma unroll
    for (int nt=0; nt<2; ++nt)
      #pragma unroll
      for (int mt=0; mt<2; ++mt){ gi[g][nt][mt]=fz; gh[g][nt][mt]=fz; }

  __syncthreads();   // staging (vmcnt) + agg ds_writes (lgkm) visible

  #pragma unroll
  for (int kk=0; kk<6; ++kk){
    half8 a[2];
    #pragma unroll
    for (int mt=0;mt<2;++mt)
      a[mt] = *(const half8*)&A1[(((kk*4+kg)*32) + mt*16 + col)*8];
    #pragma unroll
    for (int g=0; g<3; ++g)
      #pragma unroll
      for (int nt=0; nt<2; ++nt){
        int j = g*128 + wave*32 + nt*16 + col;
        half8 b = *(const half8*)&Wihs[(size_t)((kk*4+kg)*384 + j)*8];
        #pragma unroll
        for (int mt=0;mt<2;++mt)
          gi[g][nt][mt] = MFMA16(a[mt], b, gi[g][nt][mt]);
      }
  }
  #pragma unroll
  for (int kk=0; kk<4; ++kk){
    half8 a[2];
    #pragma unroll
    for (int mt=0;mt<2;++mt)
      a[mt] = *(const half8*)&A2[(((kk*4+kg)*32) + mt*16 + col)*8];
    #pragma unroll
    for (int g=0; g<3; ++g)
      #pragma unroll
      for (int nt=0; nt<2; ++nt){
        int j = g*128 + wave*32 + nt*16 + col;
        half8 b = *(const half8*)&Whhs[(size_t)((kk*4+kg)*384 + j)*8];
        #pragma unroll
        for (int mt=0;mt<2;++mt)
          gh[g][nt][mt] = MFMA16(a[mt], b, gh[g][nt][mt]);
      }
  }
  __syncthreads();   // all A2 (h_old) reads done before overwrite

  #pragma unroll
  for (int nt=0; nt<2; ++nt){
    int jl = wave*32 + nt*16 + col;     // feature 0..127
    float bir=b_ih[jl], biz=b_ih[128+jl], bin_=b_ih[256+jl];
    float bhr=b_hh[jl], bhz=b_hh[128+jl], bhn=b_hh[256+jl];
    #pragma unroll
    for (int mt=0; mt<2; ++mt){
      #pragma unroll
      for (int r=0; r<4; ++r){
        int e = mt*16 + kg*4 + r;
        float ir = gi[0][nt][mt][r] + bir;
        float iz = gi[1][nt][mt][r] + biz;
        float inn= gi[2][nt][mt][r] + bin_;
        float hr = gh[0][nt][mt][r] + bhr;
        float hz = gh[1][nt][mt][r] + bhz;
        float hn = gh[2][nt][mt][r] + bhn;
        float rg2 = 1.f/(1.f+__expf(-(ir+hr)));
        float zg  = 1.f/(1.f+__expf(-(iz+hz)));
        float ng  = tanhf(inn + rg2*hn);
        size_t hidx = (size_t)(n0+e)*NFEAT + jl;
        float hnew = (1.f-zg)*ng + zg*h32[hidx];
        h32[hidx] = hnew;
        h_out[hidx] = (_Float16)hnew;
        A2[(((jl>>3)*32) + e)*8 + (jl&7)] = (_Float16)hnew;
      }
    }
  }
  __syncthreads();

  // out = h_new @ W_f^T + b_f  (K=128, 64 cols; wave w owns cols w*16..+15)
  floatx4 facc[2] = {fz, fz};
  #pragma unroll
  for (int kk=0; kk<4; ++kk){
    half8 a[2];
    #pragma unroll
    for (int mt=0;mt<2;++mt)
      a[mt] = *(const half8*)&A2[(((kk*4+kg)*32) + mt*16 + col)*8];
    half8 b = *(const half8*)&Wfs[(size_t)((kk*4+kg)*64 + wave*16 + col)*8];
    #pragma unroll
    for (int mt=0;mt<2;++mt)
      facc[mt] = MFMA16(a[mt], b, facc[mt]);
  }
  float bf = b_f[wave*16+col];
  #pragma unroll
  for (int mt=0; mt<2; ++mt){
    #pragma unroll
    for (int r=0; r<4; ++r){
      int e = mt*16 + kg*4 + r;
      out[(size_t)(n0+e)*NOUTD + wave*16 + col] = facc[mt][r] + bf;
    }
  }
}

// ---------------- persistent fused kernel: 7 iterations, grid-barriered ----------------
__global__ __launch_bounds__(256,2) void fused_kernel(
    const _Float16* __restrict__ nin16,
    _Float16* __restrict__ h16b, float* __restrict__ h32,
    _Float16* __restrict__ msgsb,
    const int* __restrict__ src_csr, const int* __restrict__ dst_csr,
    const int* __restrict__ rowptr,
    const _Float16* __restrict__ W1s, const _Float16* __restrict__ W2s,
    const _Float16* __restrict__ W3s, const _Float16* __restrict__ W4s,
    const float* __restrict__ msgbias,
    const _Float16* __restrict__ Wihs, const _Float16* __restrict__ Whhs,
    const _Float16* __restrict__ Wfs,
    const float* __restrict__ b_ih, const float* __restrict__ b_hh,
    const float* __restrict__ b_f,
    float* __restrict__ out, int* __restrict__ bar){
  __shared__ __align__(16) char smem[32*CHS + 4096];   // 70656 B -> exactly 2 blocks/CU
  const int t = threadIdx.x, wave = t>>6, lane = t&63;
  // stage msg bias once into high LDS (gru phase only touches first 20 KB)
  load_lds16((const char*)msgbias + wave*1024 + lane*16, smem + 32*CHS + wave*1024);

  for (int it=0; it<NITERS; ++it){
    // write-once buffers per iteration: no stale-L2 copies possible
    const _Float16* h_in  = h16b + (size_t)it    *N_NODES*NFEAT;
    _Float16*       h_out = h16b + (size_t)(it+1)*N_NODES*NFEAT;
    _Float16*       msg_i = msgsb + (size_t)it   *N_EDGES*NEDGE;
    msg_phase(h_in, src_csr, dst_csr, W1s, W2s, W3s, W4s, msg_i, smem, wave, lane);
    gridbar(bar);                       // release-wbl2: messages in L3
    gru_phase(msg_i, rowptr, nin16, h_in, h_out, h32, Wihs, Whhs, Wfs,
              b_ih, b_hh, b_f, out + (size_t)it*N_NODES*NOUTD, smem, t, wave, lane);
    if (it < NITERS-1) gridbar(bar);    // release-wbl2: h_out in L3
  }
}

// ---------------- launch ----------------
extern "C" void kernel_launch(void* const* d_in, const int* in_sizes, int n_in,
                              void* d_out, int out_size, void* d_ws, size_t ws_size,
                              hipStream_t stream){
  (void)in_sizes; (void)n_in; (void)out_size; (void)ws_size;
  const float* node_inputs = (const float*)d_in[0];
  const int*   src_ids = (const int*)d_in[1];
  const int*   dst_ids = (const int*)d_in[2];
  const float* W1 = (const float*)d_in[3];  const float* b1 = (const float*)d_in[4];
  const float* W2 = (const float*)d_in[5];  const float* b2 = (const float*)d_in[6];
  const float* W3 = (const float*)d_in[7];  const float* b3 = (const float*)d_in[8];
  const float* W4 = (const float*)d_in[9];  const float* b4 = (const float*)d_in[10];
  const float* W_ih = (const float*)d_in[11];
  const float* W_hh = (const float*)d_in[12];
  const float* b_ih = (const float*)d_in[13];
  const float* b_hh = (const float*)d_in[14];
  const float* W_f  = (const float*)d_in[15];
  const float* b_f  = (const float*)d_in[16];
  float* out = (float*)d_out;

  char* ws = (char*)d_ws;
  auto alloc = [&](size_t b){ char* p = ws; ws += (b + 255) & ~(size_t)255; return p; };
  // 8 h16 buffers + 7 message buffers: write-once-per-launch communication
  _Float16* h16b = (_Float16*)alloc((size_t)(NITERS+1)*N_NODES*NFEAT*2);  // 33.6 MB
  _Float16* msgsb= (_Float16*)alloc((size_t)NITERS*N_EDGES*NEDGE*2);      // 117.4 MB
  float*    h32  = (float*)   alloc((size_t)N_NODES*NFEAT*4);
  _Float16* nin16= (_Float16*)alloc((size_t)N_NODES*NIN*2);
  _Float16* W1s  = (_Float16*)alloc(256*256*2);
  _Float16* W2s  = (_Float16*)alloc(256*256*2);
  _Float16* W3s  = (_Float16*)alloc(256*256*2);
  _Float16* W4s  = (_Float16*)alloc(128*256*2);
  _Float16* Wihs = (_Float16*)alloc(384*192*2);
  _Float16* Whhs = (_Float16*)alloc(384*128*2);
  _Float16* Wfs  = (_Float16*)alloc(64*128*2);
  float* msgbias = (float*)alloc(1024*4);
  int* cnt     = (int*)alloc((size_t)N_NODES*4);
  int* rowptr  = (int*)alloc((size_t)(N_NODES+1)*4);
  int* offs    = (int*)alloc((size_t)N_NODES*4);
  int* src_csr = (int*)alloc((size_t)N_EDGES*4);
  int* dst_csr = (int*)alloc((size_t)N_EDGES*4);
  int* bar     = (int*)alloc(1024);

  setup_kernel<<<8192+4096+64+176+4,256,0,stream>>>(
      node_inputs, W1,W2,W3,W4, W_ih,W_hh,W_f, b1,b2,b3,b4,
      h32, h16b, nin16, W1s,W2s,W3s,W4s, Wihs,Whhs,Wfs, msgbias, cnt);
  hist_kernel<<<N_EDGES/256,256,0,stream>>>(dst_ids, cnt);
  scan_kernel<<<1,1024,0,stream>>>(cnt, rowptr, offs, bar);
  scatter_kernel<<<N_EDGES/256,256,0,stream>>>(src_ids, dst_ids, offs, src_csr, dst_csr);

  fused_kernel<<<NBLKS,256,0,stream>>>(nin16, h16b, h32, msgsb, src_csr, dst_csr, rowptr,
                                       W1s, W2s, W3s, W4s, msgbias,
                                       Wihs, Whhs, Wfs, b_ih, b_hh, b_f, out, bar);
}

// Round 12
// 508.784 us; speedup vs baseline: 7.3307x; 3.9683x over previous
//
#include <hip/hip_runtime.h>
#include <cstdint>
#include <cstddef>

#define N_NODES 16384
#define N_EDGES 65536
#define NFEAT 128   // GRU hidden
#define NIN   64    // node inputs
#define NEDGE 128   // edge features
#define NOUTD 64    // node outputs
#define NITERS 7

#define CHS 2080    // act chunk stride bytes (128 edges * 16B + 32B pad)

typedef _Float16 half8 __attribute__((ext_vector_type(8)));
typedef _Float16 half4 __attribute__((ext_vector_type(4)));
typedef float floatx4 __attribute__((ext_vector_type(4)));

#define MFMA16(a,b,c) __builtin_amdgcn_mfma_f32_16x16x32_f16((a),(b),(c),0,0,0)

// raw barrier (no vmcnt(0) drain, unlike __syncthreads)
#define SBAR() asm volatile("s_barrier" ::: "memory")
#define WAITLGKM() asm volatile("s_waitcnt lgkmcnt(0)" ::: "memory")
#define WAITV0() asm volatile("s_waitcnt vmcnt(0)" ::: "memory")

// async global->LDS, 16B per lane. Global src per-lane; LDS dest wave-uniform base (+lane*16 by HW).
__device__ __forceinline__ void load_lds16(const void* g, void* l){
  __builtin_amdgcn_global_load_lds(
      (__attribute__((address_space(1))) void*)(uintptr_t)g,
      (__attribute__((address_space(3))) void*)l,
      16, 0, 0);
}

// ---------------- one-shot setup: inits + fp16 weight repack + bias concat ----------------
// repack: W (NOUT x KIN) f32 row-major -> [KIN/8][NOUT][8] f16
__global__ void setup_kernel(
    const float* __restrict__ node_inputs,
    const float* __restrict__ W1, const float* __restrict__ W2,
    const float* __restrict__ W3, const float* __restrict__ W4,
    const float* __restrict__ W_ih, const float* __restrict__ W_hh,
    const float* __restrict__ W_f,
    const float* __restrict__ b1, const float* __restrict__ b2,
    const float* __restrict__ b3, const float* __restrict__ b4,
    float* __restrict__ h32, _Float16* __restrict__ h16,
    _Float16* __restrict__ nin16,
    _Float16* __restrict__ W1s, _Float16* __restrict__ W2s, _Float16* __restrict__ W3s,
    _Float16* __restrict__ W4s, _Float16* __restrict__ Wihs, _Float16* __restrict__ Whhs,
    _Float16* __restrict__ Wfs, float* __restrict__ msgbias, int* __restrict__ cnt){
  int b = blockIdx.x, t = threadIdx.x;
  if (b < 8192){ int i=b*256+t; h32[i]=0.f; h16[i]=(_Float16)0.f; return; }
  b -= 8192;
  if (b < 4096){ int i=b*256+t; nin16[i] = (_Float16)node_inputs[i]; return; }
  b -= 4096;
  if (b < 64){ cnt[b*256+t] = 0; return; }
  b -= 64;
  if (b >= 176){  // bias concat: b1|b2|b3|b4 -> msgbias[1024] (zero-padded)
    int i = (b-176)*256 + t;
    float v = 0.f;
    if      (i < 256) v = b1[i];
    else if (i < 512) v = b2[i-256];
    else if (i < 768) v = b3[i-512];
    else if (i < 896) v = b4[i-768];
    msgbias[i] = v; return;
  }
  const float* W; _Float16* o; int NO, KI, base;
  if      (b < 32){ W=W1;  o=W1s;  NO=256; KI=256; base=b; }
  else if (b < 64){ W=W2;  o=W2s;  NO=256; KI=256; base=b-32; }
  else if (b < 96){ W=W3;  o=W3s;  NO=256; KI=256; base=b-64; }
  else if (b <112){ W=W4;  o=W4s;  NO=128; KI=256; base=b-96; }
  else if (b <148){ W=W_ih;o=Wihs; NO=384; KI=192; base=b-112; }
  else if (b <172){ W=W_hh;o=Whhs; NO=384; KI=128; base=b-148; }
  else            { W=W_f; o=Wfs;  NO=64;  KI=128; base=b-172; }
  int g = base*256 + t;
  int total = NO*(KI>>3);
  if (g >= total) return;
  int c = g/NO, j = g - c*NO;
  #pragma unroll
  for (int i=0;i<8;++i) o[(size_t)g*8+i] = (_Float16)W[(size_t)j*KI + c*8 + i];
}

__global__ void hist_kernel(const int* __restrict__ dst, int* __restrict__ cnt){
  int e = blockIdx.x*256+threadIdx.x; if (e<N_EDGES) atomicAdd(&cnt[dst[e]],1);
}
__global__ __launch_bounds__(1024) void scan_kernel(const int* __restrict__ cnt,
                                                    int* __restrict__ rowptr,
                                                    int* __restrict__ offs){
  __shared__ int sd[1024];
  int t = threadIdx.x;
  int c[16]; int s=0;
  #pragma unroll
  for (int k=0;k<16;++k){ c[k]=cnt[t*16+k]; s+=c[k]; }
  sd[t]=s; __syncthreads();
  for (int off=1; off<1024; off<<=1){
    int v = (t>=off)? sd[t-off]:0;
    __syncthreads();
    sd[t]+=v;
    __syncthreads();
  }
  int base = sd[t]-s; // exclusive prefix
  #pragma unroll
  for (int k=0;k<16;++k){ rowptr[t*16+k]=base; offs[t*16+k]=base; base+=c[k]; }
  if (t==0) rowptr[N_NODES]=N_EDGES;
}
// CSR permutation: src/dst ids in CSR-slot order -> msg writes message rows
// contiguously in dst-grouped order (agg reads sequentially).
__global__ void scatter_kernel(const int* __restrict__ src, const int* __restrict__ dst,
                               int* __restrict__ offs,
                               int* __restrict__ src_csr, int* __restrict__ dst_csr){
  int e = blockIdx.x*256+threadIdx.x;
  if (e<N_EDGES){
    int d = dst[e];
    int p = atomicAdd(&offs[d],1);
    src_csr[p] = src[e];
    dst_csr[p] = d;
  }
}

// ---------------- fused 4-layer edge MLP: 128 edges/block, 4 waves, 2 blocks/CU --------
// act LDS: [32 chunks][128 edges][8 halfs], chunk stride CHS (padded).
// A frags from LDS (2M x 2N wave grid). B frags: global(L2) -> VGPR, double-buffered
// one K-step ahead (2-buffer only: acc(128 AGPR)+b(64)+misc is at the 256-reg
// 2-waves/SIMD boundary; a 3rd buffer would halve occupancy). No in-loop barriers.
template<int N, int NEXTN>
__device__ __forceinline__ void run_layer(const _Float16* __restrict__ Ws,
                                          const _Float16* __restrict__ nextWs,
                                          const char* act, half8 (&b)[2][8],
                                          int wave, int lane, floatx4 (&acc)[4][8]){
  constexpr int NTW  = N/32;
  constexpr int NNTW = (NEXTN>0)? NEXTN/32 : 0;
  const int kg = lane>>4, col = lane&15;
  const int wr = wave>>1, wc = wave&1;          // 2M x 2N wave grid
  const int j0  = wc*(N/2);
  const int j0n = wc*(NEXTN/2);
  const int r0  = wr*64;
  #pragma unroll
  for (int kk=0; kk<8; ++kk){
    if (kk < 7){
      #pragma unroll
      for (int nt=0; nt<NTW; ++nt)
        b[(kk+1)&1][nt] = *(const half8*)&Ws[(size_t)(((kk+1)*4+kg)*N + j0 + nt*16 + col)*8];
    } else if constexpr (NEXTN > 0){
      #pragma unroll
      for (int nt=0; nt<NNTW; ++nt)
        b[0][nt] = *(const half8*)&nextWs[(size_t)(kg*NEXTN + j0n + nt*16 + col)*8];
    }
    half8 a[4];
    #pragma unroll
    for (int mt=0; mt<4; ++mt)
      a[mt] = *(const half8*)(act + (size_t)(kk*4+kg)*CHS + (r0 + mt*16 + col)*16);
    __builtin_amdgcn_s_setprio(1);
    #pragma unroll
    for (int nt=0; nt<NTW; ++nt)
      #pragma unroll
      for (int mt=0; mt<4; ++mt)
        acc[mt][nt] = MFMA16(a[mt], b[kk&1][nt], acc[mt][nt]);
    __builtin_amdgcn_s_setprio(0);
  }
}

template<int NTW>
__device__ __forceinline__ void epi_relu(floatx4 (&acc)[4][8], const float* __restrict__ biasf,
                                         int boff, char* act, int wave, int lane){
  const int rg = lane>>4, col = lane&15;
  const int wr = wave>>1, wc = wave&1;
  const int r0 = wr*64;
  #pragma unroll
  for (int nt=0; nt<NTW; ++nt){
    int j = wc*(NTW*16) + nt*16 + col;
    float bv = biasf[boff + j];        // LDS read (lgkm) -- keeps vmcnt clean
    char* dst = act + (size_t)(j>>3)*CHS + (j&7)*2;
    #pragma unroll
    for (int mt=0; mt<4; ++mt){
      #pragma unroll
      for (int r=0; r<4; ++r){
        int e = r0 + mt*16 + rg*4 + r;
        float v = fmaxf(acc[mt][nt][r] + bv, 0.f);
        acc[mt][nt][r] = 0.f;
        *(_Float16*)(dst + (size_t)e*16) = (_Float16)v;
      }
    }
  }
}

__global__ __launch_bounds__(256,2) void msg_kernel(
    const _Float16* __restrict__ h,
    const int* __restrict__ src_csr, const int* __restrict__ dst_csr,
    const _Float16* __restrict__ W1s, const _Float16* __restrict__ W2s,
    const _Float16* __restrict__ W3s, const _Float16* __restrict__ W4s,
    const float* __restrict__ msgbias,
    _Float16* __restrict__ messages){
  __shared__ __align__(16) char smem[32*CHS + 4096];   // 69.5KB -> 2 blocks/CU
  char* act = smem;
  const float* biasf = (const float*)(smem + 32*CHS);
  const int t = threadIdx.x, wave = t>>6, lane = t&63;
  const int kg = lane>>4, col = lane&15;
  const int wc = wave&1;
  // bijective XCD swizzle (512 blocks = 8 XCDs x 64): each XCD gets 64 contiguous
  // CSR blocks -> dst-row repeats in the h-gather hit local L2.
  const int bid = ((blockIdx.x & 7) << 6) + (blockIdx.x >> 3);
  const int e0 = bid*128;
  // stage bias concat (1024 floats; wave w loads 1KB)
  load_lds16((const char*)msgbias + wave*1024 + lane*16, smem + 32*CHS + wave*1024);
  // gather msg_in = [h[src] | h[dst]] into act chunks (0..15 src, 16..31 dst)
  {
    const int* ids = (wave < 2) ? src_csr : dst_csr;
    const int row0 = ids[e0 + lane]      * NFEAT;
    const int row1 = ids[e0 + 64 + lane] * NFEAT;
    #pragma unroll
    for (int i=0;i<8;++i){
      int c = wave*8 + i;
      int f = (c&15)*8;
      load_lds16(h + row0 + f, act + (size_t)c*CHS);
      load_lds16(h + row1 + f, act + (size_t)c*CHS + 1024);
    }
  }
  // L1 K-step-0 B prefetch (global -> regs)
  half8 b[2][8];
  #pragma unroll
  for (int nt=0; nt<8; ++nt)
    b[0][nt] = *(const half8*)&W1s[(size_t)(kg*256 + wc*128 + nt*16 + col)*8];

  floatx4 acc[4][8];
  const floatx4 fz = {0.f,0.f,0.f,0.f};
  #pragma unroll
  for (int i=0;i<4;++i)
    #pragma unroll
    for (int j=0;j<8;++j) acc[i][j] = fz;

  WAITV0(); SBAR();                    // act + bias staged everywhere

  run_layer<256,256>(W1s, W2s, act, b, wave, lane, acc);
  WAITLGKM(); SBAR();                  // all waves' act reads done
  epi_relu<8>(acc, biasf, 0, act, wave, lane);
  WAITLGKM(); SBAR();                  // epi writes visible
  run_layer<256,256>(W2s, W3s, act, b, wave, lane, acc);
  WAITLGKM(); SBAR();
  epi_relu<8>(acc, biasf, 256, act, wave, lane);
  WAITLGKM(); SBAR();
  run_layer<256,128>(W3s, W4s, act, b, wave, lane, acc);
  WAITLGKM(); SBAR();
  epi_relu<8>(acc, biasf, 512, act, wave, lane);
  WAITLGKM(); SBAR();
  run_layer<128,0>(W4s, nullptr, act, b, wave, lane, acc);
  // L4 epilogue -> messages in CSR-slot order (contiguous rows), includes b4
  {
    const int rg = lane>>4;
    const int wr = wave>>1;
    const int r0 = wr*64;
    #pragma unroll
    for (int nt=0; nt<4; ++nt){
      int j = wc*64 + nt*16 + col;
      float bv = biasf[768 + j];
      #pragma unroll
      for (int mt=0; mt<4; ++mt){
        #pragma unroll
        for (int r=0; r<4; ++r){
          int e = e0 + r0 + mt*16 + rg*4 + r;
          messages[(size_t)e*NEDGE + j] = (_Float16)(acc[mt][nt][r] + bv);
        }
      }
    }
  }
}

// ---------------- fused agg + GRU + out projection: 32 nodes/block, 4 waves, 2+/CU ------
__global__ __launch_bounds__(256,2) void gru_kernel(
    const _Float16* __restrict__ messages,
    const int* __restrict__ rowptr,
    const _Float16* __restrict__ nin16,
    _Float16* __restrict__ h16, float* __restrict__ h32,
    const _Float16* __restrict__ Wihs, const _Float16* __restrict__ Whhs,
    const _Float16* __restrict__ Wfs,
    const float* __restrict__ b_ih, const float* __restrict__ b_hh,
    const float* __restrict__ b_f,
    float* __restrict__ out){
  __shared__ __align__(16) char smem[20480];
  _Float16* A1 = (_Float16*)smem;            // [24][32][8]: 0..15 agg, 16..23 nin (12KB)
  _Float16* A2 = (_Float16*)(smem + 12288);  // [16][32][8]: h rows, then h_new (8KB)
  const int t = threadIdx.x, wave = t>>6, lane = t&63;
  const int kg = lane>>4, col = lane&15;
  const int n0 = blockIdx.x*32;
  {
    const int node = lane&31;
    // nin chunks 16..23: wave w stages chunks 16+2w,16+2w+1 in one 1KB gload_lds
    load_lds16(nin16 + (size_t)(n0+node)*NIN + (wave*2 + (lane>>5))*8,
               smem + 8192 + (size_t)wave*1024);
    // h chunks 0..15: wave w stages 4 chunks (2 gload_lds)
    #pragma unroll
    for (int ii=0; ii<2; ++ii){
      int cb = wave*4 + ii*2;
      load_lds16(h16 + (size_t)(n0+node)*NFEAT + (cb + (lane>>5))*8,
                 smem + 12288 + (size_t)cb*512);
    }
  }
  // agg: stream CSR-contiguous message rows -> A1 chunks 0..15
  {
    const int slot = t>>5, l4 = (t&31)*4;   // 8 row-slots x 32 feature-lanes
    #pragma unroll
    for (int rr=0; rr<4; ++rr){
      int nl = rr*8 + slot;
      int n = n0 + nl;
      int beg = rowptr[n], end = rowptr[n+1];
      float a0=0,a1=0,a2=0,a3=0;
      for (int idx=beg; idx<end; ++idx){
        half4 v = *(const half4*)(messages + (size_t)idx*NEDGE + l4);
        a0 += (float)v.x; a1 += (float)v.y; a2 += (float)v.z; a3 += (float)v.w;
      }
      half4 o; o.x=(_Float16)a0; o.y=(_Float16)a1; o.z=(_Float16)a2; o.w=(_Float16)a3;
      *(half4*)&A1[(size_t)((l4>>3)*32 + nl)*8 + (l4&7)] = o;
    }
  }
  floatx4 gi[3][2][2], gh[3][2][2];
  const floatx4 fz = {0.f,0.f,0.f,0.f};
  #pragma unroll
  for (int g=0; g<3; ++g)
    #pragma unroll
    for (int nt=0; nt<2; ++nt)
      #pragma unroll
      for (int mt=0; mt<2; ++mt){ gi[g][nt][mt]=fz; gh[g][nt][mt]=fz; }

  __syncthreads();   // staging (vmcnt) + agg ds_writes (lgkm) visible

  // wave w owns features w*32..w*32+31 (all 3 gates); B direct from L2
  #pragma unroll
  for (int kk=0; kk<6; ++kk){
    half8 a[2];
    #pragma unroll
    for (int mt=0;mt<2;++mt)
      a[mt] = *(const half8*)&A1[(((kk*4+kg)*32) + mt*16 + col)*8];
    #pragma unroll
    for (int g=0; g<3; ++g)
      #pragma unroll
      for (int nt=0; nt<2; ++nt){
        int j = g*128 + wave*32 + nt*16 + col;
        half8 b = *(const half8*)&Wihs[(size_t)((kk*4+kg)*384 + j)*8];
        #pragma unroll
        for (int mt=0;mt<2;++mt)
          gi[g][nt][mt] = MFMA16(a[mt], b, gi[g][nt][mt]);
      }
  }
  #pragma unroll
  for (int kk=0; kk<4; ++kk){
    half8 a[2];
    #pragma unroll
    for (int mt=0;mt<2;++mt)
      a[mt] = *(const half8*)&A2[(((kk*4+kg)*32) + mt*16 + col)*8];
    #pragma unroll
    for (int g=0; g<3; ++g)
      #pragma unroll
      for (int nt=0; nt<2; ++nt){
        int j = g*128 + wave*32 + nt*16 + col;
        half8 b = *(const half8*)&Whhs[(size_t)((kk*4+kg)*384 + j)*8];
        #pragma unroll
        for (int mt=0;mt<2;++mt)
          gh[g][nt][mt] = MFMA16(a[mt], b, gh[g][nt][mt]);
      }
  }
  __syncthreads();   // all A2 (h_old) reads done before overwrite

  #pragma unroll
  for (int nt=0; nt<2; ++nt){
    int jl = wave*32 + nt*16 + col;     // feature 0..127
    float bir=b_ih[jl], biz=b_ih[128+jl], bin_=b_ih[256+jl];
    float bhr=b_hh[jl], bhz=b_hh[128+jl], bhn=b_hh[256+jl];
    #pragma unroll
    for (int mt=0; mt<2; ++mt){
      #pragma unroll
      for (int r=0; r<4; ++r){
        int e = mt*16 + kg*4 + r;
        float ir = gi[0][nt][mt][r] + bir;
        float iz = gi[1][nt][mt][r] + biz;
        float inn= gi[2][nt][mt][r] + bin_;
        float hr = gh[0][nt][mt][r] + bhr;
        float hz = gh[1][nt][mt][r] + bhz;
        float hn = gh[2][nt][mt][r] + bhn;
        float rg2 = 1.f/(1.f+__expf(-(ir+hr)));
        float zg  = 1.f/(1.f+__expf(-(iz+hz)));
        float ng  = tanhf(inn + rg2*hn);
        size_t hidx = (size_t)(n0+e)*NFEAT + jl;
        float hnew = (1.f-zg)*ng + zg*h32[hidx];
        h32[hidx] = hnew;
        h16[hidx] = (_Float16)hnew;
        A2[(((jl>>3)*32) + e)*8 + (jl&7)] = (_Float16)hnew;
      }
    }
  }
  __syncthreads();

  // out = h_new @ W_f^T + b_f  (K=128, 64 cols; wave w owns cols w*16..+15)
  floatx4 facc[2] = {fz, fz};
  #pragma unroll
  for (int kk=0; kk<4; ++kk){
    half8 a[2];
    #pragma unroll
    for (int mt=0;mt<2;++mt)
      a[mt] = *(const half8*)&A2[(((kk*4+kg)*32) + mt*16 + col)*8];
    half8 b = *(const half8*)&Wfs[(size_t)((kk*4+kg)*64 + wave*16 + col)*8];
    #pragma unroll
    for (int mt=0;mt<2;++mt)
      facc[mt] = MFMA16(a[mt], b, facc[mt]);
  }
  float bf = b_f[wave*16+col];
  #pragma unroll
  for (int mt=0; mt<2; ++mt){
    #pragma unroll
    for (int r=0; r<4; ++r){
      int e = mt*16 + kg*4 + r;
      out[(size_t)(n0+e)*NOUTD + wave*16 + col] = facc[mt][r] + bf;
    }
  }
}

// ---------------- launch ----------------
extern "C" void kernel_launch(void* const* d_in, const int* in_sizes, int n_in,
                              void* d_out, int out_size, void* d_ws, size_t ws_size,
                              hipStream_t stream){
  (void)in_sizes; (void)n_in; (void)out_size; (void)ws_size;
  const float* node_inputs = (const float*)d_in[0];
  const int*   src_ids = (const int*)d_in[1];
  const int*   dst_ids = (const int*)d_in[2];
  const float* W1 = (const float*)d_in[3];  const float* b1 = (const float*)d_in[4];
  const float* W2 = (const float*)d_in[5];  const float* b2 = (const float*)d_in[6];
  const float* W3 = (const float*)d_in[7];  const float* b3 = (const float*)d_in[8];
  const float* W4 = (const float*)d_in[9];  const float* b4 = (const float*)d_in[10];
  const float* W_ih = (const float*)d_in[11];
  const float* W_hh = (const float*)d_in[12];
  const float* b_ih = (const float*)d_in[13];
  const float* b_hh = (const float*)d_in[14];
  const float* W_f  = (const float*)d_in[15];
  const float* b_f  = (const float*)d_in[16];
  float* out = (float*)d_out;

  char* ws = (char*)d_ws;
  auto alloc = [&](size_t b){ char* p = ws; ws += (b + 255) & ~(size_t)255; return p; };
  _Float16* h16  = (_Float16*)alloc((size_t)N_NODES*NFEAT*2);
  float*    h32  = (float*)   alloc((size_t)N_NODES*NFEAT*4);
  _Float16* nin16= (_Float16*)alloc((size_t)N_NODES*NIN*2);
  _Float16* msgs = (_Float16*)alloc((size_t)N_EDGES*NEDGE*2);
  _Float16* W1s  = (_Float16*)alloc(256*256*2);
  _Float16* W2s  = (_Float16*)alloc(256*256*2);
  _Float16* W3s  = (_Float16*)alloc(256*256*2);
  _Float16* W4s  = (_Float16*)alloc(128*256*2);
  _Float16* Wihs = (_Float16*)alloc(384*192*2);
  _Float16* Whhs = (_Float16*)alloc(384*128*2);
  _Float16* Wfs  = (_Float16*)alloc(64*128*2);
  float* msgbias = (float*)alloc(1024*4);
  int* cnt     = (int*)alloc((size_t)N_NODES*4);
  int* rowptr  = (int*)alloc((size_t)(N_NODES+1)*4);
  int* offs    = (int*)alloc((size_t)N_NODES*4);
  int* src_csr = (int*)alloc((size_t)N_EDGES*4);
  int* dst_csr = (int*)alloc((size_t)N_EDGES*4);

  setup_kernel<<<8192+4096+64+176+4,256,0,stream>>>(
      node_inputs, W1,W2,W3,W4, W_ih,W_hh,W_f, b1,b2,b3,b4,
      h32, h16, nin16, W1s,W2s,W3s,W4s, Wihs,Whhs,Wfs, msgbias, cnt);
  hist_kernel<<<N_EDGES/256,256,0,stream>>>(dst_ids, cnt);
  scan_kernel<<<1,1024,0,stream>>>(cnt, rowptr, offs);
  scatter_kernel<<<N_EDGES/256,256,0,stream>>>(src_ids, dst_ids, offs, src_csr, dst_csr);

  for (int it=0; it<NITERS; ++it){
    msg_kernel<<<N_EDGES/128,256,0,stream>>>(h16, src_csr, dst_csr,
                                             W1s,W2s,W3s,W4s, msgbias, msgs);
    gru_kernel<<<N_NODES/32,256,0,stream>>>(msgs, rowptr, nin16, h16, h32,
                                            Wihs, Whhs, Wfs, b_ih, b_hh, b_f,
                                            out + (size_t)it*N_NODES*NOUTD);
  }
}

// Round 13
// 431.557 us; speedup vs baseline: 8.6425x; 1.1789x over previous
//
#include <hip/hip_runtime.h>
#include <cstdint>
#include <cstddef>

#define N_NODES 16384
#define N_EDGES 65536
#define NFEAT 128   // GRU hidden
#define NIN   64    // node inputs
#define NEDGE 128   // edge features
#define NOUTD 64    // node outputs
#define NITERS 7

#define CHS 2080    // act chunk stride bytes (128 edges * 16B + 32B pad)

typedef _Float16 half8 __attribute__((ext_vector_type(8)));
typedef _Float16 half4 __attribute__((ext_vector_type(4)));
typedef float floatx4 __attribute__((ext_vector_type(4)));

#define MFMA16(a,b,c) __builtin_amdgcn_mfma_f32_16x16x32_f16((a),(b),(c),0,0,0)

// raw barrier (no vmcnt(0) drain, unlike __syncthreads)
#define SBAR() asm volatile("s_barrier" ::: "memory")
#define WAITLGKM() asm volatile("s_waitcnt lgkmcnt(0)" ::: "memory")
#define WAITV0() asm volatile("s_waitcnt vmcnt(0)" ::: "memory")

// async global->LDS, 16B per lane. Global src per-lane; LDS dest wave-uniform base (+lane*16 by HW).
__device__ __forceinline__ void load_lds16(const void* g, void* l){
  __builtin_amdgcn_global_load_lds(
      (__attribute__((address_space(1))) void*)(uintptr_t)g,
      (__attribute__((address_space(3))) void*)l,
      16, 0, 0);
}

// ---------------- one-shot setup: inits + fp16 weight repack + bias concat ----------------
// repack: W (NOUT x KIN) f32 row-major -> [KIN/8][NOUT][8] f16
__global__ void setup_kernel(
    const float* __restrict__ node_inputs,
    const float* __restrict__ W1, const float* __restrict__ W2,
    const float* __restrict__ W3, const float* __restrict__ W4,
    const float* __restrict__ W_ih, const float* __restrict__ W_hh,
    const float* __restrict__ W_f,
    const float* __restrict__ b1, const float* __restrict__ b2,
    const float* __restrict__ b3, const float* __restrict__ b4,
    _Float16* __restrict__ h16,
    _Float16* __restrict__ nin16,
    _Float16* __restrict__ W1s, _Float16* __restrict__ W2s, _Float16* __restrict__ W3s,
    _Float16* __restrict__ W4s, _Float16* __restrict__ Wihs, _Float16* __restrict__ Whhs,
    _Float16* __restrict__ Wfs, float* __restrict__ msgbias, int* __restrict__ cnt){
  int b = blockIdx.x, t = threadIdx.x;
  if (b < 8192){ int i=b*256+t; h16[i]=(_Float16)0.f; return; }
  b -= 8192;
  if (b < 4096){ int i=b*256+t; nin16[i] = (_Float16)node_inputs[i]; return; }
  b -= 4096;
  if (b < 64){ cnt[b*256+t] = 0; return; }
  b -= 64;
  if (b >= 176){  // bias concat: b1|b2|b3|b4 -> msgbias[1024] (zero-padded)
    int i = (b-176)*256 + t;
    float v = 0.f;
    if      (i < 256) v = b1[i];
    else if (i < 512) v = b2[i-256];
    else if (i < 768) v = b3[i-512];
    else if (i < 896) v = b4[i-768];
    msgbias[i] = v; return;
  }
  const float* W; _Float16* o; int NO, KI, base;
  if      (b < 32){ W=W1;  o=W1s;  NO=256; KI=256; base=b; }
  else if (b < 64){ W=W2;  o=W2s;  NO=256; KI=256; base=b-32; }
  else if (b < 96){ W=W3;  o=W3s;  NO=256; KI=256; base=b-64; }
  else if (b <112){ W=W4;  o=W4s;  NO=128; KI=256; base=b-96; }
  else if (b <148){ W=W_ih;o=Wihs; NO=384; KI=192; base=b-112; }
  else if (b <172){ W=W_hh;o=Whhs; NO=384; KI=128; base=b-148; }
  else            { W=W_f; o=Wfs;  NO=64;  KI=128; base=b-172; }
  int g = base*256 + t;
  int total = NO*(KI>>3);
  if (g >= total) return;
  int c = g/NO, j = g - c*NO;
  #pragma unroll
  for (int i=0;i<8;++i) o[(size_t)g*8+i] = (_Float16)W[(size_t)j*KI + c*8 + i];
}

__global__ void hist_kernel(const int* __restrict__ dst, int* __restrict__ cnt){
  int e = blockIdx.x*256+threadIdx.x; if (e<N_EDGES) atomicAdd(&cnt[dst[e]],1);
}
__global__ __launch_bounds__(1024) void scan_kernel(const int* __restrict__ cnt,
                                                    int* __restrict__ rowptr,
                                                    int* __restrict__ offs){
  __shared__ int sd[1024];
  int t = threadIdx.x;
  int c[16]; int s=0;
  #pragma unroll
  for (int k=0;k<16;++k){ c[k]=cnt[t*16+k]; s+=c[k]; }
  sd[t]=s; __syncthreads();
  for (int off=1; off<1024; off<<=1){
    int v = (t>=off)? sd[t-off]:0;
    __syncthreads();
    sd[t]+=v;
    __syncthreads();
  }
  int base = sd[t]-s; // exclusive prefix
  #pragma unroll
  for (int k=0;k<16;++k){ rowptr[t*16+k]=base; offs[t*16+k]=base; base+=c[k]; }
  if (t==0) rowptr[N_NODES]=N_EDGES;
}
// CSR permutation: src/dst ids in CSR-slot order -> msg writes message rows
// contiguously in dst-grouped order (agg reads sequentially).
__global__ void scatter_kernel(const int* __restrict__ src, const int* __restrict__ dst,
                               int* __restrict__ offs,
                               int* __restrict__ src_csr, int* __restrict__ dst_csr){
  int e = blockIdx.x*256+threadIdx.x;
  if (e<N_EDGES){
    int d = dst[e];
    int p = atomicAdd(&offs[d],1);
    src_csr[p] = src[e];
    dst_csr[p] = d;
  }
}

// ---------------- fused 4-layer edge MLP: 128 edges/block, 4 waves, 2 blocks/CU --------
// act LDS: [32 chunks][128 edges][8 halfs], chunk stride CHS (padded).
// A frags from LDS (2M x 2N wave grid). B frags: global(L2) -> VGPR, double-buffered
// one K-step ahead. No in-loop barriers.
template<int N, int NEXTN>
__device__ __forceinline__ void run_layer(const _Float16* __restrict__ Ws,
                                          const _Float16* __restrict__ nextWs,
                                          const char* act, half8 (&b)[2][8],
                                          int wave, int lane, floatx4 (&acc)[4][8]){
  constexpr int NTW  = N/32;
  constexpr int NNTW = (NEXTN>0)? NEXTN/32 : 0;
  const int kg = lane>>4, col = lane&15;
  const int wr = wave>>1, wc = wave&1;          // 2M x 2N wave grid
  const int j0  = wc*(N/2);
  const int j0n = wc*(NEXTN/2);
  const int r0  = wr*64;
  #pragma unroll
  for (int kk=0; kk<8; ++kk){
    if (kk < 7){
      #pragma unroll
      for (int nt=0; nt<NTW; ++nt)
        b[(kk+1)&1][nt] = *(const half8*)&Ws[(size_t)(((kk+1)*4+kg)*N + j0 + nt*16 + col)*8];
    } else if constexpr (NEXTN > 0){
      #pragma unroll
      for (int nt=0; nt<NNTW; ++nt)
        b[0][nt] = *(const half8*)&nextWs[(size_t)(kg*NEXTN + j0n + nt*16 + col)*8];
    }
    half8 a[4];
    #pragma unroll
    for (int mt=0; mt<4; ++mt)
      a[mt] = *(const half8*)(act + (size_t)(kk*4+kg)*CHS + (r0 + mt*16 + col)*16);
    __builtin_amdgcn_s_setprio(1);
    #pragma unroll
    for (int nt=0; nt<NTW; ++nt)
      #pragma unroll
      for (int mt=0; mt<4; ++mt)
        acc[mt][nt] = MFMA16(a[mt], b[kk&1][nt], acc[mt][nt]);
    __builtin_amdgcn_s_setprio(0);
  }
}

template<int NTW>
__device__ __forceinline__ void epi_relu(floatx4 (&acc)[4][8], const float* __restrict__ biasf,
                                         int boff, char* act, int wave, int lane){
  const int rg = lane>>4, col = lane&15;
  const int wr = wave>>1, wc = wave&1;
  const int r0 = wr*64;
  #pragma unroll
  for (int nt=0; nt<NTW; ++nt){
    int j = wc*(NTW*16) + nt*16 + col;
    float bv = biasf[boff + j];        // LDS read (lgkm) -- keeps vmcnt clean
    char* dst = act + (size_t)(j>>3)*CHS + (j&7)*2;
    #pragma unroll
    for (int mt=0; mt<4; ++mt){
      #pragma unroll
      for (int r=0; r<4; ++r){
        int e = r0 + mt*16 + rg*4 + r;
        float v = fmaxf(acc[mt][nt][r] + bv, 0.f);
        acc[mt][nt][r] = 0.f;
        *(_Float16*)(dst + (size_t)e*16) = (_Float16)v;
      }
    }
  }
}

__global__ __launch_bounds__(256,2) void msg_kernel(
    const _Float16* __restrict__ h,
    const int* __restrict__ src_csr, const int* __restrict__ dst_csr,
    const _Float16* __restrict__ W1s, const _Float16* __restrict__ W2s,
    const _Float16* __restrict__ W3s, const _Float16* __restrict__ W4s,
    const float* __restrict__ msgbias,
    _Float16* __restrict__ messages){
  __shared__ __align__(16) char smem[32*CHS + 4096];   // 69.5KB -> 2 blocks/CU
  char* act = smem;
  const float* biasf = (const float*)(smem + 32*CHS);
  const int t = threadIdx.x, wave = t>>6, lane = t&63;
  const int kg = lane>>4, col = lane&15;
  const int wc = wave&1;
  const int e0 = blockIdx.x*128;
  // stage bias concat (1024 floats; wave w loads 1KB)
  load_lds16((const char*)msgbias + wave*1024 + lane*16, smem + 32*CHS + wave*1024);
  // gather msg_in = [h[src] | h[dst]] into act chunks (0..15 src, 16..31 dst)
  {
    const int* ids = (wave < 2) ? src_csr : dst_csr;
    const int row0 = ids[e0 + lane]      * NFEAT;
    const int row1 = ids[e0 + 64 + lane] * NFEAT;
    #pragma unroll
    for (int i=0;i<8;++i){
      int c = wave*8 + i;
      int f = (c&15)*8;
      load_lds16(h + row0 + f, act + (size_t)c*CHS);
      load_lds16(h + row1 + f, act + (size_t)c*CHS + 1024);
    }
  }
  // L1 K-step-0 B prefetch (global -> regs)
  half8 b[2][8];
  #pragma unroll
  for (int nt=0; nt<8; ++nt)
    b[0][nt] = *(const half8*)&W1s[(size_t)(kg*256 + wc*128 + nt*16 + col)*8];

  floatx4 acc[4][8];
  const floatx4 fz = {0.f,0.f,0.f,0.f};
  #pragma unroll
  for (int i=0;i<4;++i)
    #pragma unroll
    for (int j=0;j<8;++j) acc[i][j] = fz;

  WAITV0(); SBAR();                    // act + bias staged everywhere

  run_layer<256,256>(W1s, W2s, act, b, wave, lane, acc);
  WAITLGKM(); SBAR();                  // all waves' act reads done
  epi_relu<8>(acc, biasf, 0, act, wave, lane);
  WAITLGKM(); SBAR();                  // epi writes visible
  run_layer<256,256>(W2s, W3s, act, b, wave, lane, acc);
  WAITLGKM(); SBAR();
  epi_relu<8>(acc, biasf, 256, act, wave, lane);
  WAITLGKM(); SBAR();
  run_layer<256,128>(W3s, W4s, act, b, wave, lane, acc);
  WAITLGKM(); SBAR();
  epi_relu<8>(acc, biasf, 512, act, wave, lane);
  WAITLGKM(); SBAR();
  run_layer<128,0>(W4s, nullptr, act, b, wave, lane, acc);
  // L4 epilogue -> messages in CSR-slot order (contiguous rows), includes b4
  {
    const int rg = lane>>4;
    const int wr = wave>>1;
    const int r0 = wr*64;
    #pragma unroll
    for (int nt=0; nt<4; ++nt){
      int j = wc*64 + nt*16 + col;
      float bv = biasf[768 + j];
      #pragma unroll
      for (int mt=0; mt<4; ++mt){
        #pragma unroll
        for (int r=0; r<4; ++r){
          int e = e0 + r0 + mt*16 + rg*4 + r;
          messages[(size_t)e*NEDGE + j] = (_Float16)(acc[mt][nt][r] + bv);
        }
      }
    }
  }
}

// ---------------- fused agg + GRU + output projection, 64 nodes, 8 waves ----------------
// h is pure-fp16 recurrent state; h_old for the z*h_old term comes from the A2 LDS
// fragment (read-before-write, slot ownership bijective) -- no fp32 master copy,
// saves 16 MB/iter of h32 traffic.
__global__ __launch_bounds__(512,1) void gru_kernel(
    const _Float16* __restrict__ messages,
    const int* __restrict__ rowptr,
    const _Float16* __restrict__ nin16,
    _Float16* __restrict__ h16,
    const _Float16* __restrict__ Wihs, const _Float16* __restrict__ Whhs,
    const _Float16* __restrict__ Wfs,
    const float* __restrict__ b_ih, const float* __restrict__ b_hh,
    const float* __restrict__ b_f,
    float* __restrict__ out){
  __shared__ _Float16 A1[24*64*8];   // gru_in: chunks 0..15 agg, 16..23 node inputs
  __shared__ _Float16 A2[16*64*8];   // h rows (K=128); later reused for h_new
  const int t = threadIdx.x, wave = t>>6, lane = t&63;
  const int kg = lane>>4, col = lane&15;
  const int n0 = blockIdx.x*64;
  load_lds16(nin16 + (size_t)(n0+lane)*NIN + wave*8, (char*)A1 + (size_t)(16+wave)*1024);
  #pragma unroll
  for (int ii=0; ii<2; ++ii){
    int c = wave*2 + ii;
    load_lds16(h16 + (size_t)(n0+lane)*NFEAT + c*8, (char*)A2 + (size_t)c*1024);
  }
  // agg: stream CSR-contiguous message rows -> A1 chunks 0..15
  {
    const int slot = t>>5, l4 = (t&31)*4;   // 16 row-slots x 32 feature-lanes
    #pragma unroll
    for (int rr=0; rr<4; ++rr){
      int nl = rr*16 + slot;
      int n = n0 + nl;
      int beg = rowptr[n], end = rowptr[n+1];
      float a0=0,a1=0,a2=0,a3=0;
      for (int idx=beg; idx<end; ++idx){
        half4 v = *(const half4*)(messages + (size_t)idx*NEDGE + l4);
        a0 += (float)v.x; a1 += (float)v.y; a2 += (float)v.z; a3 += (float)v.w;
      }
      half4 o; o.x=(_Float16)a0; o.y=(_Float16)a1; o.z=(_Float16)a2; o.w=(_Float16)a3;
      *(half4*)&A1[(size_t)((l4>>3)*64 + nl)*8 + (l4&7)] = o;
    }
  }
  floatx4 gi[3][4], gh[3][4];
  const floatx4 fz = {0.f,0.f,0.f,0.f};
  #pragma unroll
  for (int g=0; g<3; ++g)
    #pragma unroll
    for (int mt=0; mt<4; ++mt){ gi[g][mt]=fz; gh[g][mt]=fz; }

  __syncthreads();   // staging (vmcnt) + agg ds_writes (lgkm) all visible

  // wave w owns features w*16..w*16+15 (all 3 gates)
  #pragma unroll
  for (int kk=0; kk<6; ++kk){
    half8 a[4];
    #pragma unroll
    for (int mt=0;mt<4;++mt)
      a[mt] = *(const half8*)&A1[(((kk*4+kg)*64) + mt*16 + col)*8];
    #pragma unroll
    for (int g=0; g<3; ++g){
      int j = g*128 + wave*16 + col;
      half8 b = *(const half8*)&Wihs[(size_t)((kk*4+kg)*384 + j)*8];
      #pragma unroll
      for (int mt=0;mt<4;++mt)
        gi[g][mt] = MFMA16(a[mt], b, gi[g][mt]);
    }
  }
  #pragma unroll
  for (int kk=0; kk<4; ++kk){
    half8 a[4];
    #pragma unroll
    for (int mt=0;mt<4;++mt)
      a[mt] = *(const half8*)&A2[(((kk*4+kg)*64) + mt*16 + col)*8];
    #pragma unroll
    for (int g=0; g<3; ++g){
      int j = g*128 + wave*16 + col;
      half8 b = *(const half8*)&Whhs[(size_t)((kk*4+kg)*384 + j)*8];
      #pragma unroll
      for (int mt=0;mt<4;++mt)
        gh[g][mt] = MFMA16(a[mt], b, gh[g][mt]);
    }
  }
  __syncthreads();   // all A2 (h_old) MFMA reads done before overwrite

  // gates + h update; h_old from A2 LDS (read-before-write, unique slot per thread);
  // h_new -> global fp16 and back into A2 for the W_f GEMM
  {
    int jl = wave*16 + col;     // feature 0..127
    float bir=b_ih[jl], biz=b_ih[128+jl], bin_=b_ih[256+jl];
    float bhr=b_hh[jl], bhz=b_hh[128+jl], bhn=b_hh[256+jl];
    #pragma unroll
    for (int mt=0; mt<4; ++mt){
      #pragma unroll
      for (int r=0; r<4; ++r){
        int e = mt*16 + kg*4 + r;
        float ir = gi[0][mt][r] + bir;
        float iz = gi[1][mt][r] + biz;
        float inn= gi[2][mt][r] + bin_;
        float hr = gh[0][mt][r] + bhr;
        float hz = gh[1][mt][r] + bhz;
        float hn = gh[2][mt][r] + bhn;
        float rg2 = 1.f/(1.f+__expf(-(ir+hr)));
        float zg  = 1.f/(1.f+__expf(-(iz+hz)));
        float ng  = tanhf(inn + rg2*hn);
        size_t slot = (size_t)(((jl>>3)*64) + e)*8 + (jl&7);
        float hold = (float)A2[slot];
        float hnew = (1.f-zg)*ng + zg*hold;
        h16[(size_t)(n0+e)*NFEAT + jl] = (_Float16)hnew;
        A2[slot] = (_Float16)hnew;
      }
    }
  }
  __syncthreads();

  // out = h_new @ W_f^T + b_f  (K=128 -> 64 cols; waves 0..3 own 16 cols each)
  if (wave < 4){
    floatx4 facc[4];
    #pragma unroll
    for (int mt=0;mt<4;++mt) facc[mt]=fz;
    #pragma unroll
    for (int kk=0; kk<4; ++kk){
      half8 a[4];
      #pragma unroll
      for (int mt=0;mt<4;++mt)
        a[mt] = *(const half8*)&A2[(((kk*4+kg)*64) + mt*16 + col)*8];
      half8 b = *(const half8*)&Wfs[(size_t)((kk*4+kg)*64 + wave*16 + col)*8];
      #pragma unroll
      for (int mt=0;mt<4;++mt)
        facc[mt] = MFMA16(a[mt], b, facc[mt]);
    }
    float bf = b_f[wave*16+col];
    #pragma unroll
    for (int mt=0; mt<4; ++mt){
      #pragma unroll
      for (int r=0; r<4; ++r){
        int e = mt*16 + kg*4 + r;
        out[(size_t)(n0+e)*NOUTD + wave*16 + col] = facc[mt][r] + bf;
      }
    }
  }
}

// ---------------- launch ----------------
extern "C" void kernel_launch(void* const* d_in, const int* in_sizes, int n_in,
                              void* d_out, int out_size, void* d_ws, size_t ws_size,
                              hipStream_t stream){
  (void)in_sizes; (void)n_in; (void)out_size; (void)ws_size;
  const float* node_inputs = (const float*)d_in[0];
  const int*   src_ids = (const int*)d_in[1];
  const int*   dst_ids = (const int*)d_in[2];
  const float* W1 = (const float*)d_in[3];  const float* b1 = (const float*)d_in[4];
  const float* W2 = (const float*)d_in[5];  const float* b2 = (const float*)d_in[6];
  const float* W3 = (const float*)d_in[7];  const float* b3 = (const float*)d_in[8];
  const float* W4 = (const float*)d_in[9];  const float* b4 = (const float*)d_in[10];
  const float* W_ih = (const float*)d_in[11];
  const float* W_hh = (const float*)d_in[12];
  const float* b_ih = (const float*)d_in[13];
  const float* b_hh = (const float*)d_in[14];
  const float* W_f  = (const float*)d_in[15];
  const float* b_f  = (const float*)d_in[16];
  float* out = (float*)d_out;

  char* ws = (char*)d_ws;
  auto alloc = [&](size_t b){ char* p = ws; ws += (b + 255) & ~(size_t)255; return p; };
  _Float16* h16  = (_Float16*)alloc((size_t)N_NODES*NFEAT*2);
  _Float16* nin16= (_Float16*)alloc((size_t)N_NODES*NIN*2);
  _Float16* msgs = (_Float16*)alloc((size_t)N_EDGES*NEDGE*2);
  _Float16* W1s  = (_Float16*)alloc(256*256*2);
  _Float16* W2s  = (_Float16*)alloc(256*256*2);
  _Float16* W3s  = (_Float16*)alloc(256*256*2);
  _Float16* W4s  = (_Float16*)alloc(128*256*2);
  _Float16* Wihs = (_Float16*)alloc(384*192*2);
  _Float16* Whhs = (_Float16*)alloc(384*128*2);
  _Float16* Wfs  = (_Float16*)alloc(64*128*2);
  float* msgbias = (float*)alloc(1024*4);
  int* cnt     = (int*)alloc((size_t)N_NODES*4);
  int* rowptr  = (int*)alloc((size_t)(N_NODES+1)*4);
  int* offs    = (int*)alloc((size_t)N_NODES*4);
  int* src_csr = (int*)alloc((size_t)N_EDGES*4);
  int* dst_csr = (int*)alloc((size_t)N_EDGES*4);

  setup_kernel<<<8192+4096+64+176+4,256,0,stream>>>(
      node_inputs, W1,W2,W3,W4, W_ih,W_hh,W_f, b1,b2,b3,b4,
      h16, nin16, W1s,W2s,W3s,W4s, Wihs,Whhs,Wfs, msgbias, cnt);
  hist_kernel<<<N_EDGES/256,256,0,stream>>>(dst_ids, cnt);
  scan_kernel<<<1,1024,0,stream>>>(cnt, rowptr, offs);
  scatter_kernel<<<N_EDGES/256,256,0,stream>>>(src_ids, dst_ids, offs, src_csr, dst_csr);

  for (int it=0; it<NITERS; ++it){
    msg_kernel<<<N_EDGES/128,256,0,stream>>>(h16, src_csr, dst_csr,
                                             W1s,W2s,W3s,W4s, msgbias, msgs);
    gru_kernel<<<N_NODES/64,512,0,stream>>>(msgs, rowptr, nin16, h16,
                                            Wihs, Whhs, Wfs, b_ih, b_hh, b_f,
                                            out + (size_t)it*N_NODES*NOUTD);
  }
}